// Round 2
// baseline (2627.552 us; speedup 1.0000x reference)
//
#include <hip/hip_runtime.h>

// EntropicOTQuantileRegression — fp32 baseline.
// One block per output row i. Two [32,128]@[128,128] fp32 register-tiled
// GEMMs per j-tile, W1/W2 resident in LDS (151KiB dynamic), online
// logsumexp over j. No workspace used; all 1024 outputs written each call.

#define NPTS 1024
#define FDIM 64
#define RDIM 8
#define HID  128
#define TJ   32
#define NTHREADS 256
#define EPS_F 0.1f
#define INV_EPS 10.0f

__device__ __forceinline__ float sp(float x) {
    // softplus, same stable form as jax.nn.softplus
    return fmaxf(x, 0.0f) + log1pf(expf(-fabsf(x)));
}

__device__ __forceinline__ void gemm4x4(const float* __restrict__ A,
                                        const float* __restrict__ W,
                                        int m0, int n0, float acc[4][4]) {
#pragma unroll
    for (int r = 0; r < 4; ++r)
#pragma unroll
        for (int c = 0; c < 4; ++c) acc[r][c] = 0.0f;

    const float* Am = A + m0 * HID;
#pragma unroll 4
    for (int kq = 0; kq < HID / 4; ++kq) {
        const int k0 = kq * 4;
        const float4 a0 = *(const float4*)&Am[0 * HID + k0];
        const float4 a1 = *(const float4*)&Am[1 * HID + k0];
        const float4 a2 = *(const float4*)&Am[2 * HID + k0];
        const float4 a3 = *(const float4*)&Am[3 * HID + k0];
        const float4 wv0 = *(const float4*)&W[(k0 + 0) * HID + n0];
        const float4 wv1 = *(const float4*)&W[(k0 + 1) * HID + n0];
        const float4 wv2 = *(const float4*)&W[(k0 + 2) * HID + n0];
        const float4 wv3 = *(const float4*)&W[(k0 + 3) * HID + n0];
        // q-major emission: 16 independent FMAs between revisits of an acc
#define MACQ(Q, WV)                                                          \
        acc[0][0] += a0.Q * WV.x; acc[0][1] += a0.Q * WV.y;                  \
        acc[0][2] += a0.Q * WV.z; acc[0][3] += a0.Q * WV.w;                  \
        acc[1][0] += a1.Q * WV.x; acc[1][1] += a1.Q * WV.y;                  \
        acc[1][2] += a1.Q * WV.z; acc[1][3] += a1.Q * WV.w;                  \
        acc[2][0] += a2.Q * WV.x; acc[2][1] += a2.Q * WV.y;                  \
        acc[2][2] += a2.Q * WV.z; acc[2][3] += a2.Q * WV.w;                  \
        acc[3][0] += a3.Q * WV.x; acc[3][1] += a3.Q * WV.y;                  \
        acc[3][2] += a3.Q * WV.z; acc[3][3] += a3.Q * WV.w;
        MACQ(x, wv0)
        MACQ(y, wv1)
        MACQ(z, wv2)
        MACQ(w, wv3)
#undef MACQ
    }
}

__global__ __launch_bounds__(NTHREADS, 1)
void eotqr_kernel(const float* __restrict__ Xg, const float* __restrict__ Ug,
                  const float* __restrict__ Yg, const float* __restrict__ W0g,
                  const float* __restrict__ b0g, const float* __restrict__ W1g,
                  const float* __restrict__ b1g, const float* __restrict__ W2g,
                  const float* __restrict__ b2g, const float* __restrict__ Woutg,
                  const float* __restrict__ boutg, float* __restrict__ outg) {
    extern __shared__ float smem[];
    float* w1    = smem;                  // 16384
    float* w2    = w1 + HID * HID;        // 16384
    float* hbuf  = w2 + HID * HID;        // TJ*HID = 4096 (h0 then h1, in place)
    float* w0r   = hbuf + TJ * HID;       // RDIM*HID = 1024 (W0 rows 64..71)
    float* b1s   = w0r + RDIM * HID;      // 128
    float* b2s   = b1s + HID;             // 128
    float* wouts = b2s + HID;             // 128
    float* hXi   = wouts + HID;           // 128 (X_i @ W0[:64] + b0)
    float* ytile = hXi + HID;             // TJ*RDIM = 256
    float* slackl = ytile + TJ * RDIM;    // TJ

    const int tid = threadIdx.x;
    const int i   = blockIdx.x;

    // ---- per-block staging ----
    {
        const float4* s1 = (const float4*)W1g;
        const float4* s2 = (const float4*)W2g;
        float4* d1 = (float4*)w1;
        float4* d2 = (float4*)w2;
        for (int e = tid; e < HID * HID / 4; e += NTHREADS) {
            d1[e] = s1[e];
            d2[e] = s2[e];
        }
    }
    for (int e = tid; e < RDIM * HID; e += NTHREADS) w0r[e] = W0g[FDIM * HID + e];
    for (int e = tid; e < HID; e += NTHREADS) {
        b1s[e] = b1g[e];
        b2s[e] = b2g[e];
        wouts[e] = Woutg[e];
        float a = b0g[e];
        for (int f = 0; f < FDIM; ++f) a += Xg[i * FDIM + f] * W0g[f * HID + e];
        hXi[e] = a;  // b0 folded in
    }
    float Ui[RDIM];
#pragma unroll
    for (int r = 0; r < RDIM; ++r) Ui[r] = Ug[i * RDIM + r];
    const float bout0 = boutg[0];

    const int n_idx = tid & 31;
    const int m_idx = tid >> 5;
    const int m0 = m_idx * 4;   // local-j rows owned (4)
    const int n0 = n_idx * 4;   // hidden cols owned (4)

    float m_run = -INFINITY, s_run = 0.0f;

    __syncthreads();

    for (int jt = 0; jt < NPTS / TJ; ++jt) {
        // stage Y tile (also used for the cost dot later)
        for (int e = tid; e < TJ * RDIM; e += NTHREADS)
            ytile[e] = Yg[jt * TJ * RDIM + e];
        __syncthreads();

        // phase A: h0 = sp(hXi + Y_j @ W0r)
        for (int e = tid; e < TJ * (HID / 4); e += NTHREADS) {
            const int jl = e >> 5;
            const int k0 = (e & 31) * 4;
            float4 a = *(const float4*)&hXi[k0];
#pragma unroll
            for (int r = 0; r < RDIM; ++r) {
                const float yv = ytile[jl * RDIM + r];
                const float4 w = *(const float4*)&w0r[r * HID + k0];
                a.x += yv * w.x; a.y += yv * w.y;
                a.z += yv * w.z; a.w += yv * w.w;
            }
            float4 hq = make_float4(sp(a.x), sp(a.y), sp(a.z), sp(a.w));
            *(float4*)&hbuf[jl * HID + k0] = hq;
        }
        __syncthreads();

        // GEMM1: h1 = sp(h0 @ W1 + b1)
        float acc[4][4];
        gemm4x4(hbuf, w1, m0, n0, acc);
        __syncthreads();  // all reads of h0 done before overwrite
#pragma unroll
        for (int r = 0; r < 4; ++r) {
            float4 hv;
            hv.x = sp(acc[r][0] + b1s[n0 + 0]);
            hv.y = sp(acc[r][1] + b1s[n0 + 1]);
            hv.z = sp(acc[r][2] + b1s[n0 + 2]);
            hv.w = sp(acc[r][3] + b1s[n0 + 3]);
            *(float4*)&hbuf[(m0 + r) * HID + n0] = hv;
        }
        __syncthreads();

        // GEMM2: h2 = sp(h1 @ W2 + b2); psi = h2 . Wout + bout
        gemm4x4(hbuf, w2, m0, n0, acc);
        float p[4];
#pragma unroll
        for (int r = 0; r < 4; ++r) {
            float s = 0.0f;
#pragma unroll
            for (int c = 0; c < 4; ++c)
                s += sp(acc[r][c] + b2s[n0 + c]) * wouts[n0 + c];
            p[r] = s;
        }
#pragma unroll
        for (int off = 16; off > 0; off >>= 1)
#pragma unroll
            for (int r = 0; r < 4; ++r) p[r] += __shfl_down(p[r], off, 32);
        if (n_idx == 0) {
#pragma unroll
            for (int r = 0; r < 4; ++r) {
                const int jl = m0 + r;
                float cost = 0.0f;
#pragma unroll
                for (int rr = 0; rr < RDIM; ++rr)
                    cost += Ui[rr] * ytile[jl * RDIM + rr];
                slackl[jl] = cost - (p[r] + bout0);
            }
        }
        __syncthreads();

        // phase D: online logsumexp update (wave 0, lanes 0..31)
        if (tid < TJ) {
            const float s = slackl[tid];
            float tmax = s;
#pragma unroll
            for (int off = 16; off > 0; off >>= 1)
                tmax = fmaxf(tmax, __shfl_xor(tmax, off, 32));
            const float nm = fmaxf(m_run, tmax);
            float e = expf((s - nm) * INV_EPS);
#pragma unroll
            for (int off = 16; off > 0; off >>= 1)
                e += __shfl_xor(e, off, 32);
            s_run = s_run * expf((m_run - nm) * INV_EPS) + e;
            m_run = nm;
        }
        __syncthreads();
    }

    if (tid == 0)
        outg[i] = EPS_F * (logf(s_run) - logf((float)NPTS)) + m_run;
}

extern "C" void kernel_launch(void* const* d_in, const int* in_sizes, int n_in,
                              void* d_out, int out_size, void* d_ws, size_t ws_size,
                              hipStream_t stream) {
    const float* X    = (const float*)d_in[0];
    const float* U    = (const float*)d_in[1];
    const float* Y    = (const float*)d_in[2];
    const float* W0   = (const float*)d_in[3];
    const float* b0   = (const float*)d_in[4];
    const float* W1   = (const float*)d_in[5];
    const float* b1   = (const float*)d_in[6];
    const float* W2   = (const float*)d_in[7];
    const float* b2   = (const float*)d_in[8];
    const float* Wout = (const float*)d_in[9];
    const float* bout = (const float*)d_in[10];
    float* out = (float*)d_out;

    const size_t lds_bytes =
        (size_t)(2 * HID * HID + TJ * HID + RDIM * HID + 4 * HID + TJ * RDIM + TJ) *
        sizeof(float);  // 154,752 B

    // opt in to >64KB dynamic LDS (ignore error if unsupported/no-op on ROCm)
    (void)hipFuncSetAttribute((const void*)eotqr_kernel,
                              hipFuncAttributeMaxDynamicSharedMemorySize,
                              (int)lds_bytes);

    hipLaunchKernelGGL(eotqr_kernel, dim3(NPTS), dim3(NTHREADS), lds_bytes, stream,
                       X, U, Y, W0, b0, W1, b1, W2, b2, Wout, bout, out);
}

// Round 3
// 1346.121 us; speedup vs baseline: 1.9519x; 1.9519x over previous
//
#include <hip/hip_runtime.h>

// EntropicOTQuantileRegression — bf16-MFMA with hi/lo fp32 split (3-product).
// Transposed formulation: per layer C[hid_out][j] = W^T @ H, W-frags register-
// resident, H (hi/lo bf16) in XOR-swizzled LDS. One block per output row i,
// TJ=128 j-tile, 512 threads (8 waves as 4 mg x 2 ng), online logsumexp.

#define NPTS 1024
#define FDIM 64
#define RDIM 8
#define HID  128
#define TJ   128
#define NTH  512
#define EPS_F 0.1f
#define INV_EPS 10.0f

typedef __attribute__((ext_vector_type(8))) short short8;   // 8 bf16 (4 VGPR)
typedef __attribute__((ext_vector_type(4))) float f32x4;    // MFMA C/D

// LDS byte offsets
#define OFF_H0HI 0
#define OFF_H0LO 32768
#define OFF_H1HI 65536
#define OFF_H1LO 98304
#define OFF_YT   131072   // 128*8 f32   = 4096
#define OFF_PSI  135168   // 4*128 f32   = 2048
#define OFF_SLK  137216   // 128 f32     = 512
#define OFF_HXI  137728   // 128 f32
#define OFF_B1   138240
#define OFF_B2   138752
#define OFF_WOUT 139264
#define OFF_UI   139776   // 8 f32
#define OFF_W0R  139808   // 8*128 f32   = 4096 (fallback path)
#define LDS_BYTES 143904

__device__ __forceinline__ float sp(float x) {
    return fmaxf(x, 0.0f) + log1pf(expf(-fabsf(x)));   // jax.nn.softplus
}
__device__ __forceinline__ unsigned bcu(float x) { return __builtin_bit_cast(unsigned, x); }
__device__ __forceinline__ float bcf(unsigned x) { return __builtin_bit_cast(float, x); }
__device__ __forceinline__ unsigned short bf16rne(float x) {
    unsigned u = bcu(x);
    return (unsigned short)((u + 0x7FFFu + ((u >> 16) & 1u)) >> 16);
}
__device__ __forceinline__ void hilo(float x, unsigned short& h, unsigned short& l) {
    unsigned u = bcu(x);
    unsigned hb = (u + 0x7FFFu + ((u >> 16) & 1u)) & 0xFFFF0000u;
    h = (unsigned short)(hb >> 16);
    l = bf16rne(x - bcf(hb));
}
// byte address of element (j, byte-offset-in-row) in a [128][128]bf16 H array,
// XOR-swizzled so frag reads/writes are bank-conflict-free. Same formula on
// both sides (rule: both-sides-or-neither).
__device__ __forceinline__ int hswz(int j, int off) {
    return j * 256 + (off ^ ((j & 7) << 4));
}

// pre-kernel: hX[n][c] = b0[c] + X[n]@W0[:64,c] ; hY[n][c] = Y[n]@W0[64:,c]
__global__ void eotqr_pre(const float* __restrict__ Xg, const float* __restrict__ Yg,
                          const float* __restrict__ W0g, const float* __restrict__ b0g,
                          float* __restrict__ hX, float* __restrict__ hY) {
    const int n = blockIdx.x, c = threadIdx.x;
    float a = b0g[c];
    for (int f = 0; f < FDIM; ++f) a += Xg[n * FDIM + f] * W0g[f * HID + c];
    hX[n * HID + c] = a;
    float b = 0.0f;
#pragma unroll
    for (int r = 0; r < RDIM; ++r) b += Yg[n * RDIM + r] * W0g[(FDIM + r) * HID + c];
    hY[n * HID + c] = b;
}

template <bool USE_WS>
__global__ __launch_bounds__(NTH, 2)
void eotqr_mfma(const float* __restrict__ Xg, const float* __restrict__ Ug,
                const float* __restrict__ Yg, const float* __restrict__ W0g,
                const float* __restrict__ b0g, const float* __restrict__ W1g,
                const float* __restrict__ b1g, const float* __restrict__ W2g,
                const float* __restrict__ b2g, const float* __restrict__ Woutg,
                const float* __restrict__ boutg, const float* __restrict__ hXg,
                const float* __restrict__ hYg, float* __restrict__ outg) {
    extern __shared__ __align__(16) char smem[];
    float* yt    = (float*)(smem + OFF_YT);
    float* psi_p = (float*)(smem + OFF_PSI);
    float* slk   = (float*)(smem + OFF_SLK);
    float* hXi_s = (float*)(smem + OFF_HXI);
    float* b1s   = (float*)(smem + OFF_B1);
    float* b2s   = (float*)(smem + OFF_B2);
    float* wouts = (float*)(smem + OFF_WOUT);
    float* Ui_s  = (float*)(smem + OFF_UI);
    float* w0r   = (float*)(smem + OFF_W0R);
    float* wstage = (float*)smem;            // init-time overlay on H0 region

    const int tid  = threadIdx.x;
    const int i    = blockIdx.x;
    const int lane = tid & 63;
    const int wid  = tid >> 6;      // 0..7
    const int mg   = wid >> 1;      // 0..3 : owns hid-tiles {2mg, 2mg+1}
    const int ng   = wid & 1;       // 0..1 : owns j range [64*ng, 64*ng+64)

    // ---- small staging ----
    if (tid < HID) {
        b1s[tid] = b1g[tid]; b2s[tid] = b2g[tid]; wouts[tid] = Woutg[tid];
        if (USE_WS) {
            hXi_s[tid] = hXg[i * HID + tid];
        } else {
            float a = b0g[tid];
            for (int f = 0; f < FDIM; ++f) a += Xg[i * FDIM + f] * W0g[f * HID + tid];
            hXi_s[tid] = a;
        }
    }
    if (tid < RDIM) Ui_s[tid] = Ug[i * RDIM + tid];
    if (!USE_WS)
        for (int e = tid; e < RDIM * HID; e += NTH) w0r[e] = W0g[FDIM * HID + e];
    const float bout0 = boutg[0];

    // ---- build register-resident W^T fragments (hi/lo), via LDS stage ----
    // A-frag (16x16x32): m = lane&15 (+16*mtile), k = (lane>>4)*8 + e.
    // A[m=hid_out][k=hid_in] = W[k][m].
    short8 wf[2][2][4][2];  // [layer][mt][ks][hi/lo] = 128 VGPR
#pragma unroll
    for (int l = 0; l < 2; ++l) {
        const float* wsrc = l ? W2g : W1g;
        __syncthreads();
        for (int e = tid; e < HID * HID / 4; e += NTH)
            ((float4*)wstage)[e] = ((const float4*)wsrc)[e];
        __syncthreads();
#pragma unroll
        for (int mt = 0; mt < 2; ++mt)
#pragma unroll
            for (int ks = 0; ks < 4; ++ks) {
                union { unsigned short u[8]; short8 v; } ph, pl;
#pragma unroll
                for (int e = 0; e < 8; ++e) {
                    const int k = ks * 32 + (lane >> 4) * 8 + e;
                    const int m = (mg * 2 + mt) * 16 + (lane & 15);
                    hilo(wstage[k * HID + m], ph.u[e], pl.u[e]);
                }
                wf[l][mt][ks][0] = ph.v;
                wf[l][mt][ks][1] = pl.v;
            }
    }
    __syncthreads();

    float m_run = -INFINITY, s_run = 0.0f;

#pragma unroll 1
    for (int jt = 0; jt < NPTS / TJ; ++jt) {
        // ---- stage Y tile, zero psi partials ----
        ((float2*)yt)[tid] = ((const float2*)(Yg + jt * TJ * RDIM))[tid];
        psi_p[tid] = 0.0f;
        __syncthreads();

        // ---- layer 0: H0[j][c] = sp(hX_i[c] + hY_j[c]) -> hi/lo bf16 ----
        {
            const int j = tid >> 2;
#pragma unroll
            for (int q = 0; q < 8; ++q) {
                const int c = (tid & 3) * 4 + q * 16;
                float4 v;
                if (USE_WS) {
                    const float4 hy = *(const float4*)(hYg + (size_t)(jt * TJ + j) * HID + c);
                    const float4 hx = *(const float4*)(hXi_s + c);
                    v = make_float4(hx.x + hy.x, hx.y + hy.y, hx.z + hy.z, hx.w + hy.w);
                } else {
                    v = *(const float4*)(hXi_s + c);
#pragma unroll
                    for (int r = 0; r < RDIM; ++r) {
                        const float yv = yt[j * RDIM + r];
                        const float4 w = *(const float4*)(w0r + r * HID + c);
                        v.x += yv * w.x; v.y += yv * w.y; v.z += yv * w.z; v.w += yv * w.w;
                    }
                }
                union { unsigned short u[4]; ushort4 v4; } uh, ul;
                float vv[4] = {v.x, v.y, v.z, v.w};
#pragma unroll
                for (int e = 0; e < 4; ++e) hilo(sp(vv[e]), uh.u[e], ul.u[e]);
                const int a = hswz(j, c * 2);
                *(ushort4*)(smem + OFF_H0HI + a) = uh.v4;
                *(ushort4*)(smem + OFF_H0LO + a) = ul.v4;
            }
        }
        __syncthreads();

        f32x4 acc[2][4];
        // ---- layer 1: C = W1^T @ H0 (3-product hi/lo) ----
#pragma unroll
        for (int mt = 0; mt < 2; ++mt)
#pragma unroll
            for (int nt = 0; nt < 4; ++nt) acc[mt][nt] = f32x4{0.f, 0.f, 0.f, 0.f};
#pragma unroll
        for (int ks = 0; ks < 4; ++ks) {
            short8 bh[4], bl[4];
#pragma unroll
            for (int nt = 0; nt < 4; ++nt) {
                const int j = ng * 64 + nt * 16 + (lane & 15);
                const int a = hswz(j, ks * 64 + (lane >> 4) * 16);
                bh[nt] = *(const short8*)(smem + OFF_H0HI + a);
                bl[nt] = *(const short8*)(smem + OFF_H0LO + a);
            }
#pragma unroll
            for (int mt = 0; mt < 2; ++mt)
#pragma unroll
                for (int nt = 0; nt < 4; ++nt) {
                    acc[mt][nt] = __builtin_amdgcn_mfma_f32_16x16x32_bf16(
                        wf[0][mt][ks][0], bh[nt], acc[mt][nt], 0, 0, 0);
                    acc[mt][nt] = __builtin_amdgcn_mfma_f32_16x16x32_bf16(
                        wf[0][mt][ks][1], bh[nt], acc[mt][nt], 0, 0, 0);
                    acc[mt][nt] = __builtin_amdgcn_mfma_f32_16x16x32_bf16(
                        wf[0][mt][ks][0], bl[nt], acc[mt][nt], 0, 0, 0);
                }
        }
        // bias + softplus + hi/lo -> H1  (C rows = 4 consecutive hid -> b64)
#pragma unroll
        for (int mt = 0; mt < 2; ++mt)
#pragma unroll
            for (int nt = 0; nt < 4; ++nt) {
                const int r0 = (mg * 2 + mt) * 16 + (lane >> 4) * 4;
                const int j  = ng * 64 + nt * 16 + (lane & 15);
                union { unsigned short u[4]; ushort4 v4; } uh, ul;
#pragma unroll
                for (int e = 0; e < 4; ++e)
                    hilo(sp(acc[mt][nt][e] + b1s[r0 + e]), uh.u[e], ul.u[e]);
                const int a = hswz(j, r0 * 2);
                *(ushort4*)(smem + OFF_H1HI + a) = uh.v4;
                *(ushort4*)(smem + OFF_H1LO + a) = ul.v4;
            }
        __syncthreads();

        // ---- layer 2: C = W2^T @ H1 ----
#pragma unroll
        for (int mt = 0; mt < 2; ++mt)
#pragma unroll
            for (int nt = 0; nt < 4; ++nt) acc[mt][nt] = f32x4{0.f, 0.f, 0.f, 0.f};
#pragma unroll
        for (int ks = 0; ks < 4; ++ks) {
            short8 bh[4], bl[4];
#pragma unroll
            for (int nt = 0; nt < 4; ++nt) {
                const int j = ng * 64 + nt * 16 + (lane & 15);
                const int a = hswz(j, ks * 64 + (lane >> 4) * 16);
                bh[nt] = *(const short8*)(smem + OFF_H1HI + a);
                bl[nt] = *(const short8*)(smem + OFF_H1LO + a);
            }
#pragma unroll
            for (int mt = 0; mt < 2; ++mt)
#pragma unroll
                for (int nt = 0; nt < 4; ++nt) {
                    acc[mt][nt] = __builtin_amdgcn_mfma_f32_16x16x32_bf16(
                        wf[1][mt][ks][0], bh[nt], acc[mt][nt], 0, 0, 0);
                    acc[mt][nt] = __builtin_amdgcn_mfma_f32_16x16x32_bf16(
                        wf[1][mt][ks][1], bh[nt], acc[mt][nt], 0, 0, 0);
                    acc[mt][nt] = __builtin_amdgcn_mfma_f32_16x16x32_bf16(
                        wf[1][mt][ks][0], bl[nt], acc[mt][nt], 0, 0, 0);
                }
        }
        // psi partials: sum over this wave's hid rows of sp(c+b2)*wout
        float p[4];
#pragma unroll
        for (int nt = 0; nt < 4; ++nt) {
            p[nt] = 0.0f;
#pragma unroll
            for (int mt = 0; mt < 2; ++mt) {
                const int r0 = (mg * 2 + mt) * 16 + (lane >> 4) * 4;
#pragma unroll
                for (int e = 0; e < 4; ++e)
                    p[nt] += sp(acc[mt][nt][e] + b2s[r0 + e]) * wouts[r0 + e];
            }
            p[nt] += __shfl_xor(p[nt], 16);
            p[nt] += __shfl_xor(p[nt], 32);
        }
        if (lane < 16) {
#pragma unroll
            for (int nt = 0; nt < 4; ++nt)
                psi_p[mg * 128 + ng * 64 + nt * 16 + lane] = p[nt];
        }
        __syncthreads();

        // ---- slackness ----
        if (tid < TJ) {
            const float ps = psi_p[tid] + psi_p[128 + tid] + psi_p[256 + tid] + psi_p[384 + tid];
            float cost = 0.0f;
#pragma unroll
            for (int r = 0; r < RDIM; ++r) cost += Ui_s[r] * yt[tid * RDIM + r];
            slk[tid] = cost - ps - bout0;
        }
        __syncthreads();

        // ---- online logsumexp (wave 0) ----
        if (tid < 64) {
            const float s1 = slk[tid], s2 = slk[tid + 64];
            float tmax = fmaxf(s1, s2);
#pragma unroll
            for (int off = 32; off > 0; off >>= 1) tmax = fmaxf(tmax, __shfl_xor(tmax, off));
            const float nm = fmaxf(m_run, tmax);
            float e = expf((s1 - nm) * INV_EPS) + expf((s2 - nm) * INV_EPS);
#pragma unroll
            for (int off = 32; off > 0; off >>= 1) e += __shfl_xor(e, off);
            s_run = s_run * expf((m_run - nm) * INV_EPS) + e;
            m_run = nm;
        }
        __syncthreads();
    }

    if (tid == 0)
        outg[i] = EPS_F * (logf(s_run) - logf((float)NPTS)) + m_run;
}

extern "C" void kernel_launch(void* const* d_in, const int* in_sizes, int n_in,
                              void* d_out, int out_size, void* d_ws, size_t ws_size,
                              hipStream_t stream) {
    const float* X    = (const float*)d_in[0];
    const float* U    = (const float*)d_in[1];
    const float* Y    = (const float*)d_in[2];
    const float* W0   = (const float*)d_in[3];
    const float* b0   = (const float*)d_in[4];
    const float* W1   = (const float*)d_in[5];
    const float* b1   = (const float*)d_in[6];
    const float* W2   = (const float*)d_in[7];
    const float* b2   = (const float*)d_in[8];
    const float* Wout = (const float*)d_in[9];
    const float* bout = (const float*)d_in[10];
    float* out = (float*)d_out;

    const size_t need_ws = (size_t)2 * NPTS * HID * sizeof(float);  // 1 MiB
    if (ws_size >= need_ws) {
        float* hX = (float*)d_ws;
        float* hY = hX + NPTS * HID;
        hipLaunchKernelGGL(eotqr_pre, dim3(NPTS), dim3(HID), 0, stream, X, Y, W0, b0, hX, hY);
        (void)hipFuncSetAttribute((const void*)eotqr_mfma<true>,
                                  hipFuncAttributeMaxDynamicSharedMemorySize, LDS_BYTES);
        hipLaunchKernelGGL(eotqr_mfma<true>, dim3(NPTS), dim3(NTH), LDS_BYTES, stream,
                           X, U, Y, W0, b0, W1, b1, W2, b2, Wout, bout, hX, hY, out);
    } else {
        (void)hipFuncSetAttribute((const void*)eotqr_mfma<false>,
                                  hipFuncAttributeMaxDynamicSharedMemorySize, LDS_BYTES);
        hipLaunchKernelGGL(eotqr_mfma<false>, dim3(NPTS), dim3(NTH), LDS_BYTES, stream,
                           X, U, Y, W0, b0, W1, b1, W2, b2, Wout, bout,
                           (const float*)nullptr, (const float*)nullptr, out);
    }
}

// Round 4
// 1344.851 us; speedup vs baseline: 1.9538x; 1.0009x over previous
//
#include <hip/hip_runtime.h>

// EntropicOTQuantileRegression — bf16-MFMA with hi/lo fp32 split (3-product).
// R4 change (only one): __launch_bounds__(512,2) -> (512,1). R3's (512,2) was
// interpreted as min-2-blocks/CU -> 4 waves/EU -> 128-VGPR cap == exactly the
// persistent W-fragment footprint -> everything transient spilled to scratch
// (WRITE_SIZE 186MB/dispatch). (512,1) gives cap 256 (or 512), demand ~230.

#define NPTS 1024
#define FDIM 64
#define RDIM 8
#define HID  128
#define TJ   128
#define NTH  512
#define EPS_F 0.1f
#define INV_EPS 10.0f

typedef __attribute__((ext_vector_type(8))) short short8;   // 8 bf16 (4 VGPR)
typedef __attribute__((ext_vector_type(4))) float f32x4;    // MFMA C/D

// LDS byte offsets
#define OFF_H0HI 0
#define OFF_H0LO 32768
#define OFF_H1HI 65536
#define OFF_H1LO 98304
#define OFF_YT   131072   // 128*8 f32   = 4096
#define OFF_PSI  135168   // 4*128 f32   = 2048
#define OFF_SLK  137216   // 128 f32     = 512
#define OFF_HXI  137728   // 128 f32
#define OFF_B1   138240
#define OFF_B2   138752
#define OFF_WOUT 139264
#define OFF_UI   139776   // 8 f32
#define OFF_W0R  139808   // 8*128 f32   = 4096 (fallback path)
#define LDS_BYTES 143904

__device__ __forceinline__ float sp(float x) {
    return fmaxf(x, 0.0f) + log1pf(expf(-fabsf(x)));   // jax.nn.softplus
}
__device__ __forceinline__ unsigned bcu(float x) { return __builtin_bit_cast(unsigned, x); }
__device__ __forceinline__ float bcf(unsigned x) { return __builtin_bit_cast(float, x); }
__device__ __forceinline__ unsigned short bf16rne(float x) {
    unsigned u = bcu(x);
    return (unsigned short)((u + 0x7FFFu + ((u >> 16) & 1u)) >> 16);
}
__device__ __forceinline__ void hilo(float x, unsigned short& h, unsigned short& l) {
    unsigned u = bcu(x);
    unsigned hb = (u + 0x7FFFu + ((u >> 16) & 1u)) & 0xFFFF0000u;
    h = (unsigned short)(hb >> 16);
    l = bf16rne(x - bcf(hb));
}
// byte address of element (j, byte-offset-in-row) in a [128][128]bf16 H array,
// XOR-swizzled; same formula on write and read sides.
__device__ __forceinline__ int hswz(int j, int off) {
    return j * 256 + (off ^ ((j & 7) << 4));
}

// pre-kernel: hX[n][c] = b0[c] + X[n]@W0[:64,c] ; hY[n][c] = Y[n]@W0[64:,c]
__global__ void eotqr_pre(const float* __restrict__ Xg, const float* __restrict__ Yg,
                          const float* __restrict__ W0g, const float* __restrict__ b0g,
                          float* __restrict__ hX, float* __restrict__ hY) {
    const int n = blockIdx.x, c = threadIdx.x;
    float a = b0g[c];
    for (int f = 0; f < FDIM; ++f) a += Xg[n * FDIM + f] * W0g[f * HID + c];
    hX[n * HID + c] = a;
    float b = 0.0f;
#pragma unroll
    for (int r = 0; r < RDIM; ++r) b += Yg[n * RDIM + r] * W0g[(FDIM + r) * HID + c];
    hY[n * HID + c] = b;
}

template <bool USE_WS>
__global__ __launch_bounds__(NTH, 1)
void eotqr_mfma(const float* __restrict__ Xg, const float* __restrict__ Ug,
                const float* __restrict__ Yg, const float* __restrict__ W0g,
                const float* __restrict__ b0g, const float* __restrict__ W1g,
                const float* __restrict__ b1g, const float* __restrict__ W2g,
                const float* __restrict__ b2g, const float* __restrict__ Woutg,
                const float* __restrict__ boutg, const float* __restrict__ hXg,
                const float* __restrict__ hYg, float* __restrict__ outg) {
    extern __shared__ __align__(16) char smem[];
    float* yt    = (float*)(smem + OFF_YT);
    float* psi_p = (float*)(smem + OFF_PSI);
    float* slk   = (float*)(smem + OFF_SLK);
    float* hXi_s = (float*)(smem + OFF_HXI);
    float* b1s   = (float*)(smem + OFF_B1);
    float* b2s   = (float*)(smem + OFF_B2);
    float* wouts = (float*)(smem + OFF_WOUT);
    float* Ui_s  = (float*)(smem + OFF_UI);
    float* w0r   = (float*)(smem + OFF_W0R);
    float* wstage = (float*)smem;            // init-time overlay on H0 region

    const int tid  = threadIdx.x;
    const int i    = blockIdx.x;
    const int lane = tid & 63;
    const int wid  = tid >> 6;      // 0..7
    const int mg   = wid >> 1;      // 0..3 : owns hid-tiles {2mg, 2mg+1}
    const int ng   = wid & 1;       // 0..1 : owns j range [64*ng, 64*ng+64)

    // ---- small staging ----
    if (tid < HID) {
        b1s[tid] = b1g[tid]; b2s[tid] = b2g[tid]; wouts[tid] = Woutg[tid];
        if (USE_WS) {
            hXi_s[tid] = hXg[i * HID + tid];
        } else {
            float a = b0g[tid];
            for (int f = 0; f < FDIM; ++f) a += Xg[i * FDIM + f] * W0g[f * HID + tid];
            hXi_s[tid] = a;
        }
    }
    if (tid < RDIM) Ui_s[tid] = Ug[i * RDIM + tid];
    if (!USE_WS)
        for (int e = tid; e < RDIM * HID; e += NTH) w0r[e] = W0g[FDIM * HID + e];
    const float bout0 = boutg[0];

    // ---- build register-resident W^T fragments (hi/lo), via LDS stage ----
    // A-frag (16x16x32): m = lane&15 (+16*mtile), k = (lane>>4)*8 + e.
    // A[m=hid_out][k=hid_in] = W[k][m].
    short8 wf[2][2][4][2];  // [layer][mt][ks][hi/lo] = 128 VGPR
#pragma unroll
    for (int l = 0; l < 2; ++l) {
        const float* wsrc = l ? W2g : W1g;
        __syncthreads();
        for (int e = tid; e < HID * HID / 4; e += NTH)
            ((float4*)wstage)[e] = ((const float4*)wsrc)[e];
        __syncthreads();
#pragma unroll
        for (int mt = 0; mt < 2; ++mt)
#pragma unroll
            for (int ks = 0; ks < 4; ++ks) {
                union { unsigned short u[8]; short8 v; } ph, pl;
#pragma unroll
                for (int e = 0; e < 8; ++e) {
                    const int k = ks * 32 + (lane >> 4) * 8 + e;
                    const int m = (mg * 2 + mt) * 16 + (lane & 15);
                    hilo(wstage[k * HID + m], ph.u[e], pl.u[e]);
                }
                wf[l][mt][ks][0] = ph.v;
                wf[l][mt][ks][1] = pl.v;
            }
    }
    __syncthreads();

    float m_run = -INFINITY, s_run = 0.0f;

#pragma unroll 1
    for (int jt = 0; jt < NPTS / TJ; ++jt) {
        // ---- stage Y tile, zero psi partials ----
        ((float2*)yt)[tid] = ((const float2*)(Yg + jt * TJ * RDIM))[tid];
        psi_p[tid] = 0.0f;
        __syncthreads();

        // ---- layer 0: H0[j][c] = sp(hX_i[c] + hY_j[c]) -> hi/lo bf16 ----
        {
            const int j = tid >> 2;
#pragma unroll
            for (int q = 0; q < 8; ++q) {
                const int c = (tid & 3) * 4 + q * 16;
                float4 v;
                if (USE_WS) {
                    const float4 hy = *(const float4*)(hYg + (size_t)(jt * TJ + j) * HID + c);
                    const float4 hx = *(const float4*)(hXi_s + c);
                    v = make_float4(hx.x + hy.x, hx.y + hy.y, hx.z + hy.z, hx.w + hy.w);
                } else {
                    v = *(const float4*)(hXi_s + c);
#pragma unroll
                    for (int r = 0; r < RDIM; ++r) {
                        const float yv = yt[j * RDIM + r];
                        const float4 w = *(const float4*)(w0r + r * HID + c);
                        v.x += yv * w.x; v.y += yv * w.y; v.z += yv * w.z; v.w += yv * w.w;
                    }
                }
                union { unsigned short u[4]; ushort4 v4; } uh, ul;
                float vv[4] = {v.x, v.y, v.z, v.w};
#pragma unroll
                for (int e = 0; e < 4; ++e) hilo(sp(vv[e]), uh.u[e], ul.u[e]);
                const int a = hswz(j, c * 2);
                *(ushort4*)(smem + OFF_H0HI + a) = uh.v4;
                *(ushort4*)(smem + OFF_H0LO + a) = ul.v4;
            }
        }
        __syncthreads();

        f32x4 acc[2][4];
        // ---- layer 1: C = W1^T @ H0 (3-product hi/lo) ----
#pragma unroll
        for (int mt = 0; mt < 2; ++mt)
#pragma unroll
            for (int nt = 0; nt < 4; ++nt) acc[mt][nt] = f32x4{0.f, 0.f, 0.f, 0.f};
#pragma unroll
        for (int ks = 0; ks < 4; ++ks) {
            short8 bh[4], bl[4];
#pragma unroll
            for (int nt = 0; nt < 4; ++nt) {
                const int j = ng * 64 + nt * 16 + (lane & 15);
                const int a = hswz(j, ks * 64 + (lane >> 4) * 16);
                bh[nt] = *(const short8*)(smem + OFF_H0HI + a);
                bl[nt] = *(const short8*)(smem + OFF_H0LO + a);
            }
#pragma unroll
            for (int mt = 0; mt < 2; ++mt)
#pragma unroll
                for (int nt = 0; nt < 4; ++nt) {
                    acc[mt][nt] = __builtin_amdgcn_mfma_f32_16x16x32_bf16(
                        wf[0][mt][ks][0], bh[nt], acc[mt][nt], 0, 0, 0);
                    acc[mt][nt] = __builtin_amdgcn_mfma_f32_16x16x32_bf16(
                        wf[0][mt][ks][1], bh[nt], acc[mt][nt], 0, 0, 0);
                    acc[mt][nt] = __builtin_amdgcn_mfma_f32_16x16x32_bf16(
                        wf[0][mt][ks][0], bl[nt], acc[mt][nt], 0, 0, 0);
                }
        }
        // bias + softplus + hi/lo -> H1  (C rows = 4 consecutive hid -> b64)
#pragma unroll
        for (int mt = 0; mt < 2; ++mt)
#pragma unroll
            for (int nt = 0; nt < 4; ++nt) {
                const int r0 = (mg * 2 + mt) * 16 + (lane >> 4) * 4;
                const int j  = ng * 64 + nt * 16 + (lane & 15);
                union { unsigned short u[4]; ushort4 v4; } uh, ul;
#pragma unroll
                for (int e = 0; e < 4; ++e)
                    hilo(sp(acc[mt][nt][e] + b1s[r0 + e]), uh.u[e], ul.u[e]);
                const int a = hswz(j, r0 * 2);
                *(ushort4*)(smem + OFF_H1HI + a) = uh.v4;
                *(ushort4*)(smem + OFF_H1LO + a) = ul.v4;
            }
        __syncthreads();

        // ---- layer 2: C = W2^T @ H1 ----
#pragma unroll
        for (int mt = 0; mt < 2; ++mt)
#pragma unroll
            for (int nt = 0; nt < 4; ++nt) acc[mt][nt] = f32x4{0.f, 0.f, 0.f, 0.f};
#pragma unroll
        for (int ks = 0; ks < 4; ++ks) {
            short8 bh[4], bl[4];
#pragma unroll
            for (int nt = 0; nt < 4; ++nt) {
                const int j = ng * 64 + nt * 16 + (lane & 15);
                const int a = hswz(j, ks * 64 + (lane >> 4) * 16);
                bh[nt] = *(const short8*)(smem + OFF_H1HI + a);
                bl[nt] = *(const short8*)(smem + OFF_H1LO + a);
            }
#pragma unroll
            for (int mt = 0; mt < 2; ++mt)
#pragma unroll
                for (int nt = 0; nt < 4; ++nt) {
                    acc[mt][nt] = __builtin_amdgcn_mfma_f32_16x16x32_bf16(
                        wf[1][mt][ks][0], bh[nt], acc[mt][nt], 0, 0, 0);
                    acc[mt][nt] = __builtin_amdgcn_mfma_f32_16x16x32_bf16(
                        wf[1][mt][ks][1], bh[nt], acc[mt][nt], 0, 0, 0);
                    acc[mt][nt] = __builtin_amdgcn_mfma_f32_16x16x32_bf16(
                        wf[1][mt][ks][0], bl[nt], acc[mt][nt], 0, 0, 0);
                }
        }
        // psi partials: sum over this wave's hid rows of sp(c+b2)*wout
        float p[4];
#pragma unroll
        for (int nt = 0; nt < 4; ++nt) {
            p[nt] = 0.0f;
#pragma unroll
            for (int mt = 0; mt < 2; ++mt) {
                const int r0 = (mg * 2 + mt) * 16 + (lane >> 4) * 4;
#pragma unroll
                for (int e = 0; e < 4; ++e)
                    p[nt] += sp(acc[mt][nt][e] + b2s[r0 + e]) * wouts[r0 + e];
            }
            p[nt] += __shfl_xor(p[nt], 16);
            p[nt] += __shfl_xor(p[nt], 32);
        }
        if (lane < 16) {
#pragma unroll
            for (int nt = 0; nt < 4; ++nt)
                psi_p[mg * 128 + ng * 64 + nt * 16 + lane] = p[nt];
        }
        __syncthreads();

        // ---- slackness ----
        if (tid < TJ) {
            const float ps = psi_p[tid] + psi_p[128 + tid] + psi_p[256 + tid] + psi_p[384 + tid];
            float cost = 0.0f;
#pragma unroll
            for (int r = 0; r < RDIM; ++r) cost += Ui_s[r] * yt[tid * RDIM + r];
            slk[tid] = cost - ps - bout0;
        }
        __syncthreads();

        // ---- online logsumexp (wave 0) ----
        if (tid < 64) {
            const float s1 = slk[tid], s2 = slk[tid + 64];
            float tmax = fmaxf(s1, s2);
#pragma unroll
            for (int off = 32; off > 0; off >>= 1) tmax = fmaxf(tmax, __shfl_xor(tmax, off));
            const float nm = fmaxf(m_run, tmax);
            float e = expf((s1 - nm) * INV_EPS) + expf((s2 - nm) * INV_EPS);
#pragma unroll
            for (int off = 32; off > 0; off >>= 1) e += __shfl_xor(e, off);
            s_run = s_run * expf((m_run - nm) * INV_EPS) + e;
            m_run = nm;
        }
        __syncthreads();
    }

    if (tid == 0)
        outg[i] = EPS_F * (logf(s_run) - logf((float)NPTS)) + m_run;
}

extern "C" void kernel_launch(void* const* d_in, const int* in_sizes, int n_in,
                              void* d_out, int out_size, void* d_ws, size_t ws_size,
                              hipStream_t stream) {
    const float* X    = (const float*)d_in[0];
    const float* U    = (const float*)d_in[1];
    const float* Y    = (const float*)d_in[2];
    const float* W0   = (const float*)d_in[3];
    const float* b0   = (const float*)d_in[4];
    const float* W1   = (const float*)d_in[5];
    const float* b1   = (const float*)d_in[6];
    const float* W2   = (const float*)d_in[7];
    const float* b2   = (const float*)d_in[8];
    const float* Wout = (const float*)d_in[9];
    const float* bout = (const float*)d_in[10];
    float* out = (float*)d_out;

    const size_t need_ws = (size_t)2 * NPTS * HID * sizeof(float);  // 1 MiB
    if (ws_size >= need_ws) {
        float* hX = (float*)d_ws;
        float* hY = hX + NPTS * HID;
        hipLaunchKernelGGL(eotqr_pre, dim3(NPTS), dim3(HID), 0, stream, X, Y, W0, b0, hX, hY);
        (void)hipFuncSetAttribute((const void*)eotqr_mfma<true>,
                                  hipFuncAttributeMaxDynamicSharedMemorySize, LDS_BYTES);
        hipLaunchKernelGGL(eotqr_mfma<true>, dim3(NPTS), dim3(NTH), LDS_BYTES, stream,
                           X, U, Y, W0, b0, W1, b1, W2, b2, Wout, bout, hX, hY, out);
    } else {
        (void)hipFuncSetAttribute((const void*)eotqr_mfma<false>,
                                  hipFuncAttributeMaxDynamicSharedMemorySize, LDS_BYTES);
        hipLaunchKernelGGL(eotqr_mfma<false>, dim3(NPTS), dim3(NTH), LDS_BYTES, stream,
                           X, U, Y, W0, b0, W1, b1, W2, b2, Wout, bout,
                           (const float*)nullptr, (const float*)nullptr, out);
    }
}

// Round 5
// 1343.985 us; speedup vs baseline: 1.9550x; 1.0006x over previous
//
#include <hip/hip_runtime.h>

// EntropicOTQuantileRegression — bf16-MFMA, hi/lo fp32 split (3-product).
// R5 change (one theory, two prongs): force the 128-VGPR W-fragment array into
// registers. (1) straight-line fragment build with literal layer indices (the
// R3/R4 build loop `wf[l]...` with barriers inside may have kept l runtime ->
// whole array demoted to scratch, rule #20). (2) amdgpu_waves_per_eu(1,2)
// replaces __launch_bounds__: occupancy here is LDS-bound at 1 block/CU
// (143KB), so telling the allocator "max 2 waves/EU" makes 230 VGPRs free.

#define NPTS 1024
#define FDIM 64
#define RDIM 8
#define HID  128
#define TJ   128
#define NTH  512
#define EPS_F 0.1f
#define INV_EPS 10.0f

typedef __attribute__((ext_vector_type(8))) short short8;   // 8 bf16 (4 VGPR)
typedef __attribute__((ext_vector_type(4))) float f32x4;    // MFMA C/D

// LDS byte offsets
#define OFF_H0HI 0
#define OFF_H0LO 32768
#define OFF_H1HI 65536
#define OFF_H1LO 98304
#define OFF_YT   131072   // 128*8 f32   = 4096
#define OFF_PSI  135168   // 4*128 f32   = 2048
#define OFF_SLK  137216   // 128 f32     = 512
#define OFF_HXI  137728   // 128 f32
#define OFF_B1   138240
#define OFF_B2   138752
#define OFF_WOUT 139264
#define OFF_UI   139776   // 8 f32
#define OFF_W0R  139808   // 8*128 f32   = 4096 (fallback path)
#define LDS_BYTES 143904

__device__ __forceinline__ float sp(float x) {
    return fmaxf(x, 0.0f) + log1pf(expf(-fabsf(x)));   // jax.nn.softplus
}
__device__ __forceinline__ unsigned bcu(float x) { return __builtin_bit_cast(unsigned, x); }
__device__ __forceinline__ float bcf(unsigned x) { return __builtin_bit_cast(float, x); }
__device__ __forceinline__ unsigned short bf16rne(float x) {
    unsigned u = bcu(x);
    return (unsigned short)((u + 0x7FFFu + ((u >> 16) & 1u)) >> 16);
}
__device__ __forceinline__ void hilo(float x, unsigned short& h, unsigned short& l) {
    unsigned u = bcu(x);
    unsigned hb = (u + 0x7FFFu + ((u >> 16) & 1u)) & 0xFFFF0000u;
    h = (unsigned short)(hb >> 16);
    l = bf16rne(x - bcf(hb));
}
// byte address of element (j, byte-offset-in-row) in a [128][128]bf16 H array,
// XOR-swizzled; same formula on write and read sides.
__device__ __forceinline__ int hswz(int j, int off) {
    return j * 256 + (off ^ ((j & 7) << 4));
}

// pre-kernel: hX[n][c] = b0[c] + X[n]@W0[:64,c] ; hY[n][c] = Y[n]@W0[64:,c]
__global__ void eotqr_pre(const float* __restrict__ Xg, const float* __restrict__ Yg,
                          const float* __restrict__ W0g, const float* __restrict__ b0g,
                          float* __restrict__ hX, float* __restrict__ hY) {
    const int n = blockIdx.x, c = threadIdx.x;
    float a = b0g[c];
    for (int f = 0; f < FDIM; ++f) a += Xg[n * FDIM + f] * W0g[f * HID + c];
    hX[n * HID + c] = a;
    float b = 0.0f;
#pragma unroll
    for (int r = 0; r < RDIM; ++r) b += Yg[n * RDIM + r] * W0g[(FDIM + r) * HID + c];
    hY[n * HID + c] = b;
}

// Stage one weight matrix into LDS, then build this wave's A-fragments
// (hi/lo) with ALL-LITERAL destination indices via macro expansion.
#define BUILD_WF(Lidx, WSRC)                                                  \
    __syncthreads();                                                          \
    for (int e = tid; e < HID * HID / 4; e += NTH)                            \
        ((float4*)wstage)[e] = ((const float4*)(WSRC))[e];                    \
    __syncthreads();                                                          \
    _Pragma("unroll")                                                         \
    for (int mt = 0; mt < 2; ++mt) {                                          \
        _Pragma("unroll")                                                     \
        for (int ks = 0; ks < 4; ++ks) {                                      \
            union { unsigned short u[8]; short8 v; } ph, pl;                  \
            _Pragma("unroll")                                                 \
            for (int e = 0; e < 8; ++e) {                                     \
                const int k = ks * 32 + (lane >> 4) * 8 + e;                  \
                const int m = (mg * 2 + mt) * 16 + (lane & 15);               \
                hilo(wstage[k * HID + m], ph.u[e], pl.u[e]);                  \
            }                                                                 \
            wf[Lidx][mt][ks][0] = ph.v;                                       \
            wf[Lidx][mt][ks][1] = pl.v;                                       \
        }                                                                     \
    }

template <bool USE_WS>
__global__
__attribute__((amdgpu_flat_work_group_size(NTH, NTH)))
__attribute__((amdgpu_waves_per_eu(1, 2)))
void eotqr_mfma(const float* __restrict__ Xg, const float* __restrict__ Ug,
                const float* __restrict__ Yg, const float* __restrict__ W0g,
                const float* __restrict__ b0g, const float* __restrict__ W1g,
                const float* __restrict__ b1g, const float* __restrict__ W2g,
                const float* __restrict__ b2g, const float* __restrict__ Woutg,
                const float* __restrict__ boutg, const float* __restrict__ hXg,
                const float* __restrict__ hYg, float* __restrict__ outg) {
    extern __shared__ __align__(16) char smem[];
    float* yt    = (float*)(smem + OFF_YT);
    float* psi_p = (float*)(smem + OFF_PSI);
    float* slk   = (float*)(smem + OFF_SLK);
    float* hXi_s = (float*)(smem + OFF_HXI);
    float* b1s   = (float*)(smem + OFF_B1);
    float* b2s   = (float*)(smem + OFF_B2);
    float* wouts = (float*)(smem + OFF_WOUT);
    float* Ui_s  = (float*)(smem + OFF_UI);
    float* w0r   = (float*)(smem + OFF_W0R);
    float* wstage = (float*)smem;            // init-time overlay on H0 region

    const int tid  = threadIdx.x;
    const int i    = blockIdx.x;
    const int lane = tid & 63;
    const int wid  = tid >> 6;      // 0..7
    const int mg   = wid >> 1;      // 0..3 : owns hid-tiles {2mg, 2mg+1}
    const int ng   = wid & 1;       // 0..1 : owns j range [64*ng, 64*ng+64)

    // ---- small staging ----
    if (tid < HID) {
        b1s[tid] = b1g[tid]; b2s[tid] = b2g[tid]; wouts[tid] = Woutg[tid];
        if (USE_WS) {
            hXi_s[tid] = hXg[i * HID + tid];
        } else {
            float a = b0g[tid];
            for (int f = 0; f < FDIM; ++f) a += Xg[i * FDIM + f] * W0g[f * HID + tid];
            hXi_s[tid] = a;
        }
    }
    if (tid < RDIM) Ui_s[tid] = Ug[i * RDIM + tid];
    if (!USE_WS)
        for (int e = tid; e < RDIM * HID; e += NTH) w0r[e] = W0g[FDIM * HID + e];
    const float bout0 = boutg[0];

    // ---- register-resident W^T fragments (hi/lo): straight-line build ----
    // A-frag (16x16x32): m = lane&15 (+16*mtile), k = (lane>>4)*8 + e.
    // A[m=hid_out][k=hid_in] = W[k][m].
    short8 wf[2][2][4][2];  // [layer][mt][ks][hi/lo] = 128 VGPR
    BUILD_WF(0, W1g)
    BUILD_WF(1, W2g)
    __syncthreads();

    float m_run = -INFINITY, s_run = 0.0f;

#pragma unroll 1
    for (int jt = 0; jt < NPTS / TJ; ++jt) {
        // ---- stage Y tile, zero psi partials ----
        ((float2*)yt)[tid] = ((const float2*)(Yg + jt * TJ * RDIM))[tid];
        psi_p[tid] = 0.0f;
        __syncthreads();

        // ---- layer 0: H0[j][c] = sp(hX_i[c] + hY_j[c]) -> hi/lo bf16 ----
        {
            const int j = tid >> 2;
#pragma unroll
            for (int q = 0; q < 8; ++q) {
                const int c = (tid & 3) * 4 + q * 16;
                float4 v;
                if (USE_WS) {
                    const float4 hy = *(const float4*)(hYg + (size_t)(jt * TJ + j) * HID + c);
                    const float4 hx = *(const float4*)(hXi_s + c);
                    v = make_float4(hx.x + hy.x, hx.y + hy.y, hx.z + hy.z, hx.w + hy.w);
                } else {
                    v = *(const float4*)(hXi_s + c);
#pragma unroll
                    for (int r = 0; r < RDIM; ++r) {
                        const float yv = yt[j * RDIM + r];
                        const float4 w = *(const float4*)(w0r + r * HID + c);
                        v.x += yv * w.x; v.y += yv * w.y; v.z += yv * w.z; v.w += yv * w.w;
                    }
                }
                union { unsigned short u[4]; ushort4 v4; } uh, ul;
                float vv[4] = {v.x, v.y, v.z, v.w};
#pragma unroll
                for (int e = 0; e < 4; ++e) hilo(sp(vv[e]), uh.u[e], ul.u[e]);
                const int a = hswz(j, c * 2);
                *(ushort4*)(smem + OFF_H0HI + a) = uh.v4;
                *(ushort4*)(smem + OFF_H0LO + a) = ul.v4;
            }
        }
        __syncthreads();

        f32x4 acc[2][4];
        // ---- layer 1: C = W1^T @ H0 (3-product hi/lo) ----
#pragma unroll
        for (int mt = 0; mt < 2; ++mt)
#pragma unroll
            for (int nt = 0; nt < 4; ++nt) acc[mt][nt] = f32x4{0.f, 0.f, 0.f, 0.f};
#pragma unroll
        for (int ks = 0; ks < 4; ++ks) {
            short8 bh[4], bl[4];
#pragma unroll
            for (int nt = 0; nt < 4; ++nt) {
                const int j = ng * 64 + nt * 16 + (lane & 15);
                const int a = hswz(j, ks * 64 + (lane >> 4) * 16);
                bh[nt] = *(const short8*)(smem + OFF_H0HI + a);
                bl[nt] = *(const short8*)(smem + OFF_H0LO + a);
            }
#pragma unroll
            for (int mt = 0; mt < 2; ++mt)
#pragma unroll
                for (int nt = 0; nt < 4; ++nt) {
                    acc[mt][nt] = __builtin_amdgcn_mfma_f32_16x16x32_bf16(
                        wf[0][mt][ks][0], bh[nt], acc[mt][nt], 0, 0, 0);
                    acc[mt][nt] = __builtin_amdgcn_mfma_f32_16x16x32_bf16(
                        wf[0][mt][ks][1], bh[nt], acc[mt][nt], 0, 0, 0);
                    acc[mt][nt] = __builtin_amdgcn_mfma_f32_16x16x32_bf16(
                        wf[0][mt][ks][0], bl[nt], acc[mt][nt], 0, 0, 0);
                }
        }
        // bias + softplus + hi/lo -> H1  (C rows = 4 consecutive hid -> b64)
#pragma unroll
        for (int mt = 0; mt < 2; ++mt)
#pragma unroll
            for (int nt = 0; nt < 4; ++nt) {
                const int r0 = (mg * 2 + mt) * 16 + (lane >> 4) * 4;
                const int j  = ng * 64 + nt * 16 + (lane & 15);
                union { unsigned short u[4]; ushort4 v4; } uh, ul;
#pragma unroll
                for (int e = 0; e < 4; ++e)
                    hilo(sp(acc[mt][nt][e] + b1s[r0 + e]), uh.u[e], ul.u[e]);
                const int a = hswz(j, r0 * 2);
                *(ushort4*)(smem + OFF_H1HI + a) = uh.v4;
                *(ushort4*)(smem + OFF_H1LO + a) = ul.v4;
            }
        __syncthreads();

        // ---- layer 2: C = W2^T @ H1 ----
#pragma unroll
        for (int mt = 0; mt < 2; ++mt)
#pragma unroll
            for (int nt = 0; nt < 4; ++nt) acc[mt][nt] = f32x4{0.f, 0.f, 0.f, 0.f};
#pragma unroll
        for (int ks = 0; ks < 4; ++ks) {
            short8 bh[4], bl[4];
#pragma unroll
            for (int nt = 0; nt < 4; ++nt) {
                const int j = ng * 64 + nt * 16 + (lane & 15);
                const int a = hswz(j, ks * 64 + (lane >> 4) * 16);
                bh[nt] = *(const short8*)(smem + OFF_H1HI + a);
                bl[nt] = *(const short8*)(smem + OFF_H1LO + a);
            }
#pragma unroll
            for (int mt = 0; mt < 2; ++mt)
#pragma unroll
                for (int nt = 0; nt < 4; ++nt) {
                    acc[mt][nt] = __builtin_amdgcn_mfma_f32_16x16x32_bf16(
                        wf[1][mt][ks][0], bh[nt], acc[mt][nt], 0, 0, 0);
                    acc[mt][nt] = __builtin_amdgcn_mfma_f32_16x16x32_bf16(
                        wf[1][mt][ks][1], bh[nt], acc[mt][nt], 0, 0, 0);
                    acc[mt][nt] = __builtin_amdgcn_mfma_f32_16x16x32_bf16(
                        wf[1][mt][ks][0], bl[nt], acc[mt][nt], 0, 0, 0);
                }
        }
        // psi partials: sum over this wave's hid rows of sp(c+b2)*wout
        float p[4];
#pragma unroll
        for (int nt = 0; nt < 4; ++nt) {
            p[nt] = 0.0f;
#pragma unroll
            for (int mt = 0; mt < 2; ++mt) {
                const int r0 = (mg * 2 + mt) * 16 + (lane >> 4) * 4;
#pragma unroll
                for (int e = 0; e < 4; ++e)
                    p[nt] += sp(acc[mt][nt][e] + b2s[r0 + e]) * wouts[r0 + e];
            }
            p[nt] += __shfl_xor(p[nt], 16);
            p[nt] += __shfl_xor(p[nt], 32);
        }
        if (lane < 16) {
#pragma unroll
            for (int nt = 0; nt < 4; ++nt)
                psi_p[mg * 128 + ng * 64 + nt * 16 + lane] = p[nt];
        }
        __syncthreads();

        // ---- slackness ----
        if (tid < TJ) {
            const float ps = psi_p[tid] + psi_p[128 + tid] + psi_p[256 + tid] + psi_p[384 + tid];
            float cost = 0.0f;
#pragma unroll
            for (int r = 0; r < RDIM; ++r) cost += Ui_s[r] * yt[tid * RDIM + r];
            slk[tid] = cost - ps - bout0;
        }
        __syncthreads();

        // ---- online logsumexp (wave 0) ----
        if (tid < 64) {
            const float s1 = slk[tid], s2 = slk[tid + 64];
            float tmax = fmaxf(s1, s2);
#pragma unroll
            for (int off = 32; off > 0; off >>= 1) tmax = fmaxf(tmax, __shfl_xor(tmax, off));
            const float nm = fmaxf(m_run, tmax);
            float e = expf((s1 - nm) * INV_EPS) + expf((s2 - nm) * INV_EPS);
#pragma unroll
            for (int off = 32; off > 0; off >>= 1) e += __shfl_xor(e, off);
            s_run = s_run * expf((m_run - nm) * INV_EPS) + e;
            m_run = nm;
        }
        __syncthreads();
    }

    if (tid == 0)
        outg[i] = EPS_F * (logf(s_run) - logf((float)NPTS)) + m_run;
}

extern "C" void kernel_launch(void* const* d_in, const int* in_sizes, int n_in,
                              void* d_out, int out_size, void* d_ws, size_t ws_size,
                              hipStream_t stream) {
    const float* X    = (const float*)d_in[0];
    const float* U    = (const float*)d_in[1];
    const float* Y    = (const float*)d_in[2];
    const float* W0   = (const float*)d_in[3];
    const float* b0   = (const float*)d_in[4];
    const float* W1   = (const float*)d_in[5];
    const float* b1   = (const float*)d_in[6];
    const float* W2   = (const float*)d_in[7];
    const float* b2   = (const float*)d_in[8];
    const float* Wout = (const float*)d_in[9];
    const float* bout = (const float*)d_in[10];
    float* out = (float*)d_out;

    const size_t need_ws = (size_t)2 * NPTS * HID * sizeof(float);  // 1 MiB
    if (ws_size >= need_ws) {
        float* hX = (float*)d_ws;
        float* hY = hX + NPTS * HID;
        hipLaunchKernelGGL(eotqr_pre, dim3(NPTS), dim3(HID), 0, stream, X, Y, W0, b0, hX, hY);
        (void)hipFuncSetAttribute((const void*)eotqr_mfma<true>,
                                  hipFuncAttributeMaxDynamicSharedMemorySize, LDS_BYTES);
        hipLaunchKernelGGL(eotqr_mfma<true>, dim3(NPTS), dim3(NTH), LDS_BYTES, stream,
                           X, U, Y, W0, b0, W1, b1, W2, b2, Wout, bout, hX, hY, out);
    } else {
        (void)hipFuncSetAttribute((const void*)eotqr_mfma<false>,
                                  hipFuncAttributeMaxDynamicSharedMemorySize, LDS_BYTES);
        hipLaunchKernelGGL(eotqr_mfma<false>, dim3(NPTS), dim3(NTH), LDS_BYTES, stream,
                           X, U, Y, W0, b0, W1, b1, W2, b2, Wout, bout,
                           (const float*)nullptr, (const float*)nullptr, out);
    }
}

// Round 6
// 1284.322 us; speedup vs baseline: 2.0459x; 1.0465x over previous
//
#include <hip/hip_runtime.h>

// EntropicOTQuantileRegression — bf16-MFMA, hi/lo fp32 split (3-product).
// R6 restructure: fit register demand under the 128-VGPR allocation the
// compiler insists on (R4/R5 proved the budget cannot be raised from source).
//   - W-hi fragments (both layers) in registers: 64 VGPR.
//   - W-lo fragments in LDS, fragment-linear (conflict-free ds_read_b128),
//     read once per (mt,ks) per layer.
//   - H0/H1 share ONE hi/lo LDS buffer in-place (barrier between layer-1
//     reads and its writes) to fit 160KiB LDS.
// Products per k-step: Whi*Hhi + Wlo*Hhi + Whi*Hlo (residual ~2^-18).

#define NPTS 1024
#define FDIM 64
#define RDIM 8
#define HID  128
#define TJ   128
#define NTH  512
#define EPS_F 0.1f
#define INV_EPS 10.0f

typedef __attribute__((ext_vector_type(8))) short short8;   // 8 bf16 (4 VGPR)
typedef __attribute__((ext_vector_type(4))) float f32x4;    // MFMA C/D

// LDS byte offsets
#define OFF_HHI  0        // 32768: H hi (H0 then H1 in-place)
#define OFF_HLO  32768    // 32768: H lo
#define OFF_WLO1 65536    // 32768: W1-lo frags, fragment-linear
#define OFF_WLO2 98304    // 32768: W2-lo frags
#define OFF_YT   131072   // 128*8 f32 = 4096
#define OFF_PSI  135168   // 4*128 f32 = 2048
#define OFF_SLK  137216   // 128 f32   = 512
#define OFF_HXI  137728   // 128 f32
#define OFF_B1   138240
#define OFF_B2   138752
#define OFF_WOUT 139264
#define OFF_UI   139776   // 8 f32
#define OFF_W0R  139808   // 8*128 f32 = 4096 (fallback path)
#define LDS_BYTES 143904  // < 163840

__device__ __forceinline__ float sp(float x) {
    return fmaxf(x, 0.0f) + log1pf(expf(-fabsf(x)));   // jax.nn.softplus
}
__device__ __forceinline__ unsigned bcu(float x) { return __builtin_bit_cast(unsigned, x); }
__device__ __forceinline__ float bcf(unsigned x) { return __builtin_bit_cast(float, x); }
__device__ __forceinline__ unsigned short bf16rne(float x) {
    unsigned u = bcu(x);
    return (unsigned short)((u + 0x7FFFu + ((u >> 16) & 1u)) >> 16);
}
__device__ __forceinline__ void hilo(float x, unsigned short& h, unsigned short& l) {
    unsigned u = bcu(x);
    unsigned hb = (u + 0x7FFFu + ((u >> 16) & 1u)) & 0xFFFF0000u;
    h = (unsigned short)(hb >> 16);
    l = bf16rne(x - bcf(hb));
}
// byte address of element (j, byte-offset-in-row) in a [128 j][128 k]bf16 H
// array, XOR-swizzled; same formula on write and read sides.
__device__ __forceinline__ int hswz(int j, int off) {
    return j * 256 + (off ^ ((j & 7) << 4));
}
// fragment-linear W-lo slot: frag (mtg in 0..7, ks in 0..3), lane
__device__ __forceinline__ int wlo_off(int base, int mtg, int ks, int lane) {
    return base + ((mtg * 4 + ks) * 64 + lane) * 16;
}

// pre-kernel: hX[n][c] = b0[c] + X[n]@W0[:64,c] ; hY[n][c] = Y[n]@W0[64:,c]
__global__ void eotqr_pre(const float* __restrict__ Xg, const float* __restrict__ Yg,
                          const float* __restrict__ W0g, const float* __restrict__ b0g,
                          float* __restrict__ hX, float* __restrict__ hY) {
    const int n = blockIdx.x, c = threadIdx.x;
    float a = b0g[c];
    for (int f = 0; f < FDIM; ++f) a += Xg[n * FDIM + f] * W0g[f * HID + c];
    hX[n * HID + c] = a;
    float b = 0.0f;
#pragma unroll
    for (int r = 0; r < RDIM; ++r) b += Yg[n * RDIM + r] * W0g[(FDIM + r) * HID + c];
    hY[n * HID + c] = b;
}

// Stage W (fp32) into LDS scratch, build this wave's A-frags: hi -> registers
// (whi[Lidx]), lo -> LDS fragment-linear at WLOOFF. Literal indices only.
#define BUILD_WF(Lidx, WSRC, WLOOFF)                                          \
    __syncthreads();                                                          \
    for (int e = tid; e < HID * HID / 4; e += NTH)                            \
        ((float4*)wstage)[e] = ((const float4*)(WSRC))[e];                    \
    __syncthreads();                                                          \
    _Pragma("unroll")                                                         \
    for (int mt = 0; mt < 2; ++mt) {                                          \
        _Pragma("unroll")                                                     \
        for (int ks = 0; ks < 4; ++ks) {                                      \
            union { unsigned short u[8]; short8 v; } ph, pl;                  \
            _Pragma("unroll")                                                 \
            for (int e = 0; e < 8; ++e) {                                     \
                const int k = ks * 32 + (lane >> 4) * 8 + e;                  \
                const int m = (mg * 2 + mt) * 16 + (lane & 15);               \
                hilo(wstage[k * HID + m], ph.u[e], pl.u[e]);                  \
            }                                                                 \
            whi[Lidx][mt][ks] = ph.v;                                         \
            if (ng == 0)                                                      \
                *(short8*)(smem + wlo_off(WLOOFF, mg * 2 + mt, ks, lane)) = pl.v; \
        }                                                                     \
    }

// One layer's GEMM: acc[mt][nt] += 3-product over k. B from H (hi/lo), W-lo
// from LDS frags, W-hi from registers. L is a literal.
#define GEMM_LAYER(L, WLOOFF)                                                 \
    _Pragma("unroll")                                                         \
    for (int mt = 0; mt < 2; ++mt)                                            \
        _Pragma("unroll")                                                     \
        for (int nt = 0; nt < 4; ++nt) acc[mt][nt] = f32x4{0.f, 0.f, 0.f, 0.f}; \
    _Pragma("unroll")                                                         \
    for (int ntp = 0; ntp < 2; ++ntp) {                                       \
        _Pragma("unroll")                                                     \
        for (int ks = 0; ks < 4; ++ks) {                                      \
            const int j0 = ng * 64 + (ntp * 2) * 16 + (lane & 15);            \
            const int ko = ks * 64 + (lane >> 4) * 16;                        \
            const short8 bh0 = *(const short8*)(smem + OFF_HHI + hswz(j0, ko));      \
            const short8 bh1 = *(const short8*)(smem + OFF_HHI + hswz(j0 + 16, ko)); \
            const short8 bl0 = *(const short8*)(smem + OFF_HLO + hswz(j0, ko));      \
            const short8 bl1 = *(const short8*)(smem + OFF_HLO + hswz(j0 + 16, ko)); \
            const short8 wl0 = *(const short8*)(smem + wlo_off(WLOOFF, mg * 2 + 0, ks, lane)); \
            const short8 wl1 = *(const short8*)(smem + wlo_off(WLOOFF, mg * 2 + 1, ks, lane)); \
            acc[0][ntp * 2 + 0] = __builtin_amdgcn_mfma_f32_16x16x32_bf16(whi[L][0][ks], bh0, acc[0][ntp * 2 + 0], 0, 0, 0); \
            acc[0][ntp * 2 + 0] = __builtin_amdgcn_mfma_f32_16x16x32_bf16(wl0,           bh0, acc[0][ntp * 2 + 0], 0, 0, 0); \
            acc[0][ntp * 2 + 0] = __builtin_amdgcn_mfma_f32_16x16x32_bf16(whi[L][0][ks], bl0, acc[0][ntp * 2 + 0], 0, 0, 0); \
            acc[0][ntp * 2 + 1] = __builtin_amdgcn_mfma_f32_16x16x32_bf16(whi[L][0][ks], bh1, acc[0][ntp * 2 + 1], 0, 0, 0); \
            acc[0][ntp * 2 + 1] = __builtin_amdgcn_mfma_f32_16x16x32_bf16(wl0,           bh1, acc[0][ntp * 2 + 1], 0, 0, 0); \
            acc[0][ntp * 2 + 1] = __builtin_amdgcn_mfma_f32_16x16x32_bf16(whi[L][0][ks], bl1, acc[0][ntp * 2 + 1], 0, 0, 0); \
            acc[1][ntp * 2 + 0] = __builtin_amdgcn_mfma_f32_16x16x32_bf16(whi[L][1][ks], bh0, acc[1][ntp * 2 + 0], 0, 0, 0); \
            acc[1][ntp * 2 + 0] = __builtin_amdgcn_mfma_f32_16x16x32_bf16(wl1,           bh0, acc[1][ntp * 2 + 0], 0, 0, 0); \
            acc[1][ntp * 2 + 0] = __builtin_amdgcn_mfma_f32_16x16x32_bf16(whi[L][1][ks], bl0, acc[1][ntp * 2 + 0], 0, 0, 0); \
            acc[1][ntp * 2 + 1] = __builtin_amdgcn_mfma_f32_16x16x32_bf16(whi[L][1][ks], bh1, acc[1][ntp * 2 + 1], 0, 0, 0); \
            acc[1][ntp * 2 + 1] = __builtin_amdgcn_mfma_f32_16x16x32_bf16(wl1,           bh1, acc[1][ntp * 2 + 1], 0, 0, 0); \
            acc[1][ntp * 2 + 1] = __builtin_amdgcn_mfma_f32_16x16x32_bf16(whi[L][1][ks], bl1, acc[1][ntp * 2 + 1], 0, 0, 0); \
        }                                                                     \
    }

template <bool USE_WS>
__global__
__attribute__((amdgpu_flat_work_group_size(NTH, NTH)))
__attribute__((amdgpu_waves_per_eu(1, 2)))
void eotqr_mfma(const float* __restrict__ Xg, const float* __restrict__ Ug,
                const float* __restrict__ Yg, const float* __restrict__ W0g,
                const float* __restrict__ b0g, const float* __restrict__ W1g,
                const float* __restrict__ b1g, const float* __restrict__ W2g,
                const float* __restrict__ b2g, const float* __restrict__ Woutg,
                const float* __restrict__ boutg, const float* __restrict__ hXg,
                const float* __restrict__ hYg, float* __restrict__ outg) {
    extern __shared__ __align__(16) char smem[];
    float* yt    = (float*)(smem + OFF_YT);
    float* psi_p = (float*)(smem + OFF_PSI);
    float* slk   = (float*)(smem + OFF_SLK);
    float* hXi_s = (float*)(smem + OFF_HXI);
    float* b1s   = (float*)(smem + OFF_B1);
    float* b2s   = (float*)(smem + OFF_B2);
    float* wouts = (float*)(smem + OFF_WOUT);
    float* Ui_s  = (float*)(smem + OFF_UI);
    float* w0r   = (float*)(smem + OFF_W0R);
    float* wstage = (float*)smem;            // init-time overlay on H region

    const int tid  = threadIdx.x;
    const int i    = blockIdx.x;
    const int lane = tid & 63;
    const int wid  = tid >> 6;      // 0..7
    const int mg   = wid >> 1;      // 0..3 : owns hid-tiles {2mg, 2mg+1}
    const int ng   = wid & 1;       // 0..1 : owns j range [64*ng, 64*ng+64)

    // ---- small staging ----
    if (tid < HID) {
        b1s[tid] = b1g[tid]; b2s[tid] = b2g[tid]; wouts[tid] = Woutg[tid];
        if (USE_WS) {
            hXi_s[tid] = hXg[i * HID + tid];
        } else {
            float a = b0g[tid];
            for (int f = 0; f < FDIM; ++f) a += Xg[i * FDIM + f] * W0g[f * HID + tid];
            hXi_s[tid] = a;
        }
    }
    if (tid < RDIM) Ui_s[tid] = Ug[i * RDIM + tid];
    if (!USE_WS)
        for (int e = tid; e < RDIM * HID; e += NTH) w0r[e] = W0g[FDIM * HID + e];
    const float bout0 = boutg[0];

    // ---- W^T fragments: hi -> 64 VGPRs, lo -> LDS fragment-linear ----
    // A-frag (16x16x32): m = lane&15 (+16*mtile), k = (lane>>4)*8 + e.
    short8 whi[2][2][4];  // [layer][mt][ks] = 64 VGPR
    BUILD_WF(0, W1g, OFF_WLO1)
    BUILD_WF(1, W2g, OFF_WLO2)
    __syncthreads();

    float m_run = -INFINITY, s_run = 0.0f;

#pragma unroll 1
    for (int jt = 0; jt < NPTS / TJ; ++jt) {
        // ---- stage Y tile ----
        ((float2*)yt)[tid] = ((const float2*)(Yg + jt * TJ * RDIM))[tid];
        __syncthreads();

        // ---- layer 0: H[j][c] = sp(hX_i[c] + hY_j[c]) -> hi/lo bf16 ----
        {
            const int j = tid >> 2;
#pragma unroll
            for (int q = 0; q < 8; ++q) {
                const int c = (tid & 3) * 4 + q * 16;
                float4 v;
                if (USE_WS) {
                    const float4 hy = *(const float4*)(hYg + (size_t)(jt * TJ + j) * HID + c);
                    const float4 hx = *(const float4*)(hXi_s + c);
                    v = make_float4(hx.x + hy.x, hx.y + hy.y, hx.z + hy.z, hx.w + hy.w);
                } else {
                    v = *(const float4*)(hXi_s + c);
#pragma unroll
                    for (int r = 0; r < RDIM; ++r) {
                        const float yv = yt[j * RDIM + r];
                        const float4 w = *(const float4*)(w0r + r * HID + c);
                        v.x += yv * w.x; v.y += yv * w.y; v.z += yv * w.z; v.w += yv * w.w;
                    }
                }
                union { unsigned short u[4]; ushort4 v4; } uh, ul;
                float vv[4] = {v.x, v.y, v.z, v.w};
#pragma unroll
                for (int e = 0; e < 4; ++e) hilo(sp(vv[e]), uh.u[e], ul.u[e]);
                const int a = hswz(j, c * 2);
                *(ushort4*)(smem + OFF_HHI + a) = uh.v4;
                *(ushort4*)(smem + OFF_HLO + a) = ul.v4;
            }
        }
        __syncthreads();

        f32x4 acc[2][4];
        // ---- layer 1: C = W1^T @ H0 ----
        GEMM_LAYER(0, OFF_WLO1)
        __syncthreads();   // all H0 reads done before in-place H1 writes

        // bias + softplus + hi/lo -> H (in place)
#pragma unroll
        for (int mt = 0; mt < 2; ++mt)
#pragma unroll
            for (int nt = 0; nt < 4; ++nt) {
                const int r0 = (mg * 2 + mt) * 16 + (lane >> 4) * 4;
                const int j  = ng * 64 + nt * 16 + (lane & 15);
                union { unsigned short u[4]; ushort4 v4; } uh, ul;
#pragma unroll
                for (int e = 0; e < 4; ++e)
                    hilo(sp(acc[mt][nt][e] + b1s[r0 + e]), uh.u[e], ul.u[e]);
                const int a = hswz(j, r0 * 2);
                *(ushort4*)(smem + OFF_HHI + a) = uh.v4;
                *(ushort4*)(smem + OFF_HLO + a) = ul.v4;
            }
        __syncthreads();

        // ---- layer 2: C = W2^T @ H1 ----
        GEMM_LAYER(1, OFF_WLO2)
        // psi partials: sum over this wave's hid rows of sp(c+b2)*wout
        float p[4];
#pragma unroll
        for (int nt = 0; nt < 4; ++nt) {
            p[nt] = 0.0f;
#pragma unroll
            for (int mt = 0; mt < 2; ++mt) {
                const int r0 = (mg * 2 + mt) * 16 + (lane >> 4) * 4;
#pragma unroll
                for (int e = 0; e < 4; ++e)
                    p[nt] += sp(acc[mt][nt][e] + b2s[r0 + e]) * wouts[r0 + e];
            }
            p[nt] += __shfl_xor(p[nt], 16);
            p[nt] += __shfl_xor(p[nt], 32);
        }
        if (lane < 16) {
#pragma unroll
            for (int nt = 0; nt < 4; ++nt)
                psi_p[mg * 128 + ng * 64 + nt * 16 + lane] = p[nt];
        }
        __syncthreads();

        // ---- slackness ----
        if (tid < TJ) {
            const float ps = psi_p[tid] + psi_p[128 + tid] + psi_p[256 + tid] + psi_p[384 + tid];
            float cost = 0.0f;
#pragma unroll
            for (int r = 0; r < RDIM; ++r) cost += Ui_s[r] * yt[tid * RDIM + r];
            slk[tid] = cost - ps - bout0;
        }
        __syncthreads();

        // ---- online logsumexp (wave 0) ----
        if (tid < 64) {
            const float s1 = slk[tid], s2 = slk[tid + 64];
            float tmax = fmaxf(s1, s2);
#pragma unroll
            for (int off = 32; off > 0; off >>= 1) tmax = fmaxf(tmax, __shfl_xor(tmax, off));
            const float nm = fmaxf(m_run, tmax);
            float e = expf((s1 - nm) * INV_EPS) + expf((s2 - nm) * INV_EPS);
#pragma unroll
            for (int off = 32; off > 0; off >>= 1) e += __shfl_xor(e, off);
            s_run = s_run * expf((m_run - nm) * INV_EPS) + e;
            m_run = nm;
        }
        __syncthreads();
    }

    if (tid == 0)
        outg[i] = EPS_F * (logf(s_run) - logf((float)NPTS)) + m_run;
}

extern "C" void kernel_launch(void* const* d_in, const int* in_sizes, int n_in,
                              void* d_out, int out_size, void* d_ws, size_t ws_size,
                              hipStream_t stream) {
    const float* X    = (const float*)d_in[0];
    const float* U    = (const float*)d_in[1];
    const float* Y    = (const float*)d_in[2];
    const float* W0   = (const float*)d_in[3];
    const float* b0   = (const float*)d_in[4];
    const float* W1   = (const float*)d_in[5];
    const float* b1   = (const float*)d_in[6];
    const float* W2   = (const float*)d_in[7];
    const float* b2   = (const float*)d_in[8];
    const float* Wout = (const float*)d_in[9];
    const float* bout = (const float*)d_in[10];
    float* out = (float*)d_out;

    const size_t need_ws = (size_t)2 * NPTS * HID * sizeof(float);  // 1 MiB
    if (ws_size >= need_ws) {
        float* hX = (float*)d_ws;
        float* hY = hX + NPTS * HID;
        hipLaunchKernelGGL(eotqr_pre, dim3(NPTS), dim3(HID), 0, stream, X, Y, W0, b0, hX, hY);
        (void)hipFuncSetAttribute((const void*)eotqr_mfma<true>,
                                  hipFuncAttributeMaxDynamicSharedMemorySize, LDS_BYTES);
        hipLaunchKernelGGL(eotqr_mfma<true>, dim3(NPTS), dim3(NTH), LDS_BYTES, stream,
                           X, U, Y, W0, b0, W1, b1, W2, b2, Wout, bout, hX, hY, out);
    } else {
        (void)hipFuncSetAttribute((const void*)eotqr_mfma<false>,
                                  hipFuncAttributeMaxDynamicSharedMemorySize, LDS_BYTES);
        hipLaunchKernelGGL(eotqr_mfma<false>, dim3(NPTS), dim3(NTH), LDS_BYTES, stream,
                           X, U, Y, W0, b0, W1, b1, W2, b2, Wout, bout,
                           (const float*)nullptr, (const float*)nullptr, out);
    }
}

// Round 7
// 425.566 us; speedup vs baseline: 6.1742x; 3.0179x over previous
//
#include <hip/hip_runtime.h>

// EntropicOTQuantileRegression — bf16-MFMA, hi/lo fp32 split (3-product).
// R7 change (single variable): fast softplus. R6 counters showed VALUBusy
// ~104% with MfmaUtil 6% and no spill -> VALU-issue-bound; the ~13k
// inst/thread/tile is dominated by ~96 calls to precise expf/log1pf (~80
// inst each). Replace with v_exp_f32/v_log_f32 (__expf/__logf): sp ~7 inst.

#define NPTS 1024
#define FDIM 64
#define RDIM 8
#define HID  128
#define TJ   128
#define NTH  512
#define EPS_F 0.1f
#define INV_EPS 10.0f

typedef __attribute__((ext_vector_type(8))) short short8;   // 8 bf16 (4 VGPR)
typedef __attribute__((ext_vector_type(4))) float f32x4;    // MFMA C/D

// LDS byte offsets
#define OFF_HHI  0        // 32768: H hi (H0 then H1 in-place)
#define OFF_HLO  32768    // 32768: H lo
#define OFF_WLO1 65536    // 32768: W1-lo frags, fragment-linear
#define OFF_WLO2 98304    // 32768: W2-lo frags
#define OFF_YT   131072   // 128*8 f32 = 4096
#define OFF_PSI  135168   // 4*128 f32 = 2048
#define OFF_SLK  137216   // 128 f32   = 512
#define OFF_HXI  137728   // 128 f32
#define OFF_B1   138240
#define OFF_B2   138752
#define OFF_WOUT 139264
#define OFF_UI   139776   // 8 f32
#define OFF_W0R  139808   // 8*128 f32 = 4096 (fallback path)
#define LDS_BYTES 143904  // < 163840

// fast softplus: v_exp_f32 + v_log_f32. |err| < ~1e-7 absolute; the
// log1p->log(1+z) substitution saturates exactly where true softplus
// saturates (z < 2^-24 -> |x| > 16.6, abs err < 6e-8).
__device__ __forceinline__ float sp(float x) {
    return fmaxf(x, 0.0f) + __logf(1.0f + __expf(-fabsf(x)));
}
__device__ __forceinline__ unsigned bcu(float x) { return __builtin_bit_cast(unsigned, x); }
__device__ __forceinline__ float bcf(unsigned x) { return __builtin_bit_cast(float, x); }
__device__ __forceinline__ unsigned short bf16rne(float x) {
    unsigned u = bcu(x);
    return (unsigned short)((u + 0x7FFFu + ((u >> 16) & 1u)) >> 16);
}
__device__ __forceinline__ void hilo(float x, unsigned short& h, unsigned short& l) {
    unsigned u = bcu(x);
    unsigned hb = (u + 0x7FFFu + ((u >> 16) & 1u)) & 0xFFFF0000u;
    h = (unsigned short)(hb >> 16);
    l = bf16rne(x - bcf(hb));
}
// byte address of element (j, byte-offset-in-row) in a [128 j][128 k]bf16 H
// array, XOR-swizzled; same formula on write and read sides.
__device__ __forceinline__ int hswz(int j, int off) {
    return j * 256 + (off ^ ((j & 7) << 4));
}
// fragment-linear W-lo slot: frag (mtg in 0..7, ks in 0..3), lane
__device__ __forceinline__ int wlo_off(int base, int mtg, int ks, int lane) {
    return base + ((mtg * 4 + ks) * 64 + lane) * 16;
}

// pre-kernel: hX[n][c] = b0[c] + X[n]@W0[:64,c] ; hY[n][c] = Y[n]@W0[64:,c]
__global__ void eotqr_pre(const float* __restrict__ Xg, const float* __restrict__ Yg,
                          const float* __restrict__ W0g, const float* __restrict__ b0g,
                          float* __restrict__ hX, float* __restrict__ hY) {
    const int n = blockIdx.x, c = threadIdx.x;
    float a = b0g[c];
    for (int f = 0; f < FDIM; ++f) a += Xg[n * FDIM + f] * W0g[f * HID + c];
    hX[n * HID + c] = a;
    float b = 0.0f;
#pragma unroll
    for (int r = 0; r < RDIM; ++r) b += Yg[n * RDIM + r] * W0g[(FDIM + r) * HID + c];
    hY[n * HID + c] = b;
}

// Stage W (fp32) into LDS scratch, build this wave's A-frags: hi -> registers
// (whi[Lidx]), lo -> LDS fragment-linear at WLOOFF. Literal indices only.
#define BUILD_WF(Lidx, WSRC, WLOOFF)                                          \
    __syncthreads();                                                          \
    for (int e = tid; e < HID * HID / 4; e += NTH)                            \
        ((float4*)wstage)[e] = ((const float4*)(WSRC))[e];                    \
    __syncthreads();                                                          \
    _Pragma("unroll")                                                         \
    for (int mt = 0; mt < 2; ++mt) {                                          \
        _Pragma("unroll")                                                     \
        for (int ks = 0; ks < 4; ++ks) {                                      \
            union { unsigned short u[8]; short8 v; } ph, pl;                  \
            _Pragma("unroll")                                                 \
            for (int e = 0; e < 8; ++e) {                                     \
                const int k = ks * 32 + (lane >> 4) * 8 + e;                  \
                const int m = (mg * 2 + mt) * 16 + (lane & 15);               \
                hilo(wstage[k * HID + m], ph.u[e], pl.u[e]);                  \
            }                                                                 \
            whi[Lidx][mt][ks] = ph.v;                                         \
            if (ng == 0)                                                      \
                *(short8*)(smem + wlo_off(WLOOFF, mg * 2 + mt, ks, lane)) = pl.v; \
        }                                                                     \
    }

// One layer's GEMM: acc[mt][nt] += 3-product over k. B from H (hi/lo), W-lo
// from LDS frags, W-hi from registers. L is a literal.
#define GEMM_LAYER(L, WLOOFF)                                                 \
    _Pragma("unroll")                                                         \
    for (int mt = 0; mt < 2; ++mt)                                            \
        _Pragma("unroll")                                                     \
        for (int nt = 0; nt < 4; ++nt) acc[mt][nt] = f32x4{0.f, 0.f, 0.f, 0.f}; \
    _Pragma("unroll")                                                         \
    for (int ntp = 0; ntp < 2; ++ntp) {                                       \
        _Pragma("unroll")                                                     \
        for (int ks = 0; ks < 4; ++ks) {                                      \
            const int j0 = ng * 64 + (ntp * 2) * 16 + (lane & 15);            \
            const int ko = ks * 64 + (lane >> 4) * 16;                        \
            const short8 bh0 = *(const short8*)(smem + OFF_HHI + hswz(j0, ko));      \
            const short8 bh1 = *(const short8*)(smem + OFF_HHI + hswz(j0 + 16, ko)); \
            const short8 bl0 = *(const short8*)(smem + OFF_HLO + hswz(j0, ko));      \
            const short8 bl1 = *(const short8*)(smem + OFF_HLO + hswz(j0 + 16, ko)); \
            const short8 wl0 = *(const short8*)(smem + wlo_off(WLOOFF, mg * 2 + 0, ks, lane)); \
            const short8 wl1 = *(const short8*)(smem + wlo_off(WLOOFF, mg * 2 + 1, ks, lane)); \
            acc[0][ntp * 2 + 0] = __builtin_amdgcn_mfma_f32_16x16x32_bf16(whi[L][0][ks], bh0, acc[0][ntp * 2 + 0], 0, 0, 0); \
            acc[0][ntp * 2 + 0] = __builtin_amdgcn_mfma_f32_16x16x32_bf16(wl0,           bh0, acc[0][ntp * 2 + 0], 0, 0, 0); \
            acc[0][ntp * 2 + 0] = __builtin_amdgcn_mfma_f32_16x16x32_bf16(whi[L][0][ks], bl0, acc[0][ntp * 2 + 0], 0, 0, 0); \
            acc[0][ntp * 2 + 1] = __builtin_amdgcn_mfma_f32_16x16x32_bf16(whi[L][0][ks], bh1, acc[0][ntp * 2 + 1], 0, 0, 0); \
            acc[0][ntp * 2 + 1] = __builtin_amdgcn_mfma_f32_16x16x32_bf16(wl0,           bh1, acc[0][ntp * 2 + 1], 0, 0, 0); \
            acc[0][ntp * 2 + 1] = __builtin_amdgcn_mfma_f32_16x16x32_bf16(whi[L][0][ks], bl1, acc[0][ntp * 2 + 1], 0, 0, 0); \
            acc[1][ntp * 2 + 0] = __builtin_amdgcn_mfma_f32_16x16x32_bf16(whi[L][1][ks], bh0, acc[1][ntp * 2 + 0], 0, 0, 0); \
            acc[1][ntp * 2 + 0] = __builtin_amdgcn_mfma_f32_16x16x32_bf16(wl1,           bh0, acc[1][ntp * 2 + 0], 0, 0, 0); \
            acc[1][ntp * 2 + 0] = __builtin_amdgcn_mfma_f32_16x16x32_bf16(whi[L][1][ks], bl0, acc[1][ntp * 2 + 0], 0, 0, 0); \
            acc[1][ntp * 2 + 1] = __builtin_amdgcn_mfma_f32_16x16x32_bf16(whi[L][1][ks], bh1, acc[1][ntp * 2 + 1], 0, 0, 0); \
            acc[1][ntp * 2 + 1] = __builtin_amdgcn_mfma_f32_16x16x32_bf16(wl1,           bh1, acc[1][ntp * 2 + 1], 0, 0, 0); \
            acc[1][ntp * 2 + 1] = __builtin_amdgcn_mfma_f32_16x16x32_bf16(whi[L][1][ks], bl1, acc[1][ntp * 2 + 1], 0, 0, 0); \
        }                                                                     \
    }

template <bool USE_WS>
__global__
__attribute__((amdgpu_flat_work_group_size(NTH, NTH)))
__attribute__((amdgpu_waves_per_eu(1, 2)))
void eotqr_mfma(const float* __restrict__ Xg, const float* __restrict__ Ug,
                const float* __restrict__ Yg, const float* __restrict__ W0g,
                const float* __restrict__ b0g, const float* __restrict__ W1g,
                const float* __restrict__ b1g, const float* __restrict__ W2g,
                const float* __restrict__ b2g, const float* __restrict__ Woutg,
                const float* __restrict__ boutg, const float* __restrict__ hXg,
                const float* __restrict__ hYg, float* __restrict__ outg) {
    extern __shared__ __align__(16) char smem[];
    float* yt    = (float*)(smem + OFF_YT);
    float* psi_p = (float*)(smem + OFF_PSI);
    float* slk   = (float*)(smem + OFF_SLK);
    float* hXi_s = (float*)(smem + OFF_HXI);
    float* b1s   = (float*)(smem + OFF_B1);
    float* b2s   = (float*)(smem + OFF_B2);
    float* wouts = (float*)(smem + OFF_WOUT);
    float* Ui_s  = (float*)(smem + OFF_UI);
    float* w0r   = (float*)(smem + OFF_W0R);
    float* wstage = (float*)smem;            // init-time overlay on H region

    const int tid  = threadIdx.x;
    const int i    = blockIdx.x;
    const int lane = tid & 63;
    const int wid  = tid >> 6;      // 0..7
    const int mg   = wid >> 1;      // 0..3 : owns hid-tiles {2mg, 2mg+1}
    const int ng   = wid & 1;       // 0..1 : owns j range [64*ng, 64*ng+64)

    // ---- small staging ----
    if (tid < HID) {
        b1s[tid] = b1g[tid]; b2s[tid] = b2g[tid]; wouts[tid] = Woutg[tid];
        if (USE_WS) {
            hXi_s[tid] = hXg[i * HID + tid];
        } else {
            float a = b0g[tid];
            for (int f = 0; f < FDIM; ++f) a += Xg[i * FDIM + f] * W0g[f * HID + tid];
            hXi_s[tid] = a;
        }
    }
    if (tid < RDIM) Ui_s[tid] = Ug[i * RDIM + tid];
    if (!USE_WS)
        for (int e = tid; e < RDIM * HID; e += NTH) w0r[e] = W0g[FDIM * HID + e];
    const float bout0 = boutg[0];

    // ---- W^T fragments: hi -> 64 VGPRs, lo -> LDS fragment-linear ----
    // A-frag (16x16x32): m = lane&15 (+16*mtile), k = (lane>>4)*8 + e.
    short8 whi[2][2][4];  // [layer][mt][ks] = 64 VGPR
    BUILD_WF(0, W1g, OFF_WLO1)
    BUILD_WF(1, W2g, OFF_WLO2)
    __syncthreads();

    float m_run = -INFINITY, s_run = 0.0f;

#pragma unroll 1
    for (int jt = 0; jt < NPTS / TJ; ++jt) {
        // ---- stage Y tile ----
        ((float2*)yt)[tid] = ((const float2*)(Yg + jt * TJ * RDIM))[tid];
        __syncthreads();

        // ---- layer 0: H[j][c] = sp(hX_i[c] + hY_j[c]) -> hi/lo bf16 ----
        {
            const int j = tid >> 2;
#pragma unroll
            for (int q = 0; q < 8; ++q) {
                const int c = (tid & 3) * 4 + q * 16;
                float4 v;
                if (USE_WS) {
                    const float4 hy = *(const float4*)(hYg + (size_t)(jt * TJ + j) * HID + c);
                    const float4 hx = *(const float4*)(hXi_s + c);
                    v = make_float4(hx.x + hy.x, hx.y + hy.y, hx.z + hy.z, hx.w + hy.w);
                } else {
                    v = *(const float4*)(hXi_s + c);
#pragma unroll
                    for (int r = 0; r < RDIM; ++r) {
                        const float yv = yt[j * RDIM + r];
                        const float4 w = *(const float4*)(w0r + r * HID + c);
                        v.x += yv * w.x; v.y += yv * w.y; v.z += yv * w.z; v.w += yv * w.w;
                    }
                }
                union { unsigned short u[4]; ushort4 v4; } uh, ul;
                float vv[4] = {v.x, v.y, v.z, v.w};
#pragma unroll
                for (int e = 0; e < 4; ++e) hilo(sp(vv[e]), uh.u[e], ul.u[e]);
                const int a = hswz(j, c * 2);
                *(ushort4*)(smem + OFF_HHI + a) = uh.v4;
                *(ushort4*)(smem + OFF_HLO + a) = ul.v4;
            }
        }
        __syncthreads();

        f32x4 acc[2][4];
        // ---- layer 1: C = W1^T @ H0 ----
        GEMM_LAYER(0, OFF_WLO1)
        __syncthreads();   // all H0 reads done before in-place H1 writes

        // bias + softplus + hi/lo -> H (in place)
#pragma unroll
        for (int mt = 0; mt < 2; ++mt)
#pragma unroll
            for (int nt = 0; nt < 4; ++nt) {
                const int r0 = (mg * 2 + mt) * 16 + (lane >> 4) * 4;
                const int j  = ng * 64 + nt * 16 + (lane & 15);
                union { unsigned short u[4]; ushort4 v4; } uh, ul;
#pragma unroll
                for (int e = 0; e < 4; ++e)
                    hilo(sp(acc[mt][nt][e] + b1s[r0 + e]), uh.u[e], ul.u[e]);
                const int a = hswz(j, r0 * 2);
                *(ushort4*)(smem + OFF_HHI + a) = uh.v4;
                *(ushort4*)(smem + OFF_HLO + a) = ul.v4;
            }
        __syncthreads();

        // ---- layer 2: C = W2^T @ H1 ----
        GEMM_LAYER(1, OFF_WLO2)
        // psi partials: sum over this wave's hid rows of sp(c+b2)*wout
        float p[4];
#pragma unroll
        for (int nt = 0; nt < 4; ++nt) {
            p[nt] = 0.0f;
#pragma unroll
            for (int mt = 0; mt < 2; ++mt) {
                const int r0 = (mg * 2 + mt) * 16 + (lane >> 4) * 4;
#pragma unroll
                for (int e = 0; e < 4; ++e)
                    p[nt] += sp(acc[mt][nt][e] + b2s[r0 + e]) * wouts[r0 + e];
            }
            p[nt] += __shfl_xor(p[nt], 16);
            p[nt] += __shfl_xor(p[nt], 32);
        }
        if (lane < 16) {
#pragma unroll
            for (int nt = 0; nt < 4; ++nt)
                psi_p[mg * 128 + ng * 64 + nt * 16 + lane] = p[nt];
        }
        __syncthreads();

        // ---- slackness ----
        if (tid < TJ) {
            const float ps = psi_p[tid] + psi_p[128 + tid] + psi_p[256 + tid] + psi_p[384 + tid];
            float cost = 0.0f;
#pragma unroll
            for (int r = 0; r < RDIM; ++r) cost += Ui_s[r] * yt[tid * RDIM + r];
            slk[tid] = cost - ps - bout0;
        }
        __syncthreads();

        // ---- online logsumexp (wave 0) ----
        if (tid < 64) {
            const float s1 = slk[tid], s2 = slk[tid + 64];
            float tmax = fmaxf(s1, s2);
#pragma unroll
            for (int off = 32; off > 0; off >>= 1) tmax = fmaxf(tmax, __shfl_xor(tmax, off));
            const float nm = fmaxf(m_run, tmax);
            float e = __expf((s1 - nm) * INV_EPS) + __expf((s2 - nm) * INV_EPS);
#pragma unroll
            for (int off = 32; off > 0; off >>= 1) e += __shfl_xor(e, off);
            s_run = s_run * __expf((m_run - nm) * INV_EPS) + e;
            m_run = nm;
        }
        __syncthreads();
    }

    if (tid == 0)
        outg[i] = EPS_F * (logf(s_run) - logf((float)NPTS)) + m_run;
}

extern "C" void kernel_launch(void* const* d_in, const int* in_sizes, int n_in,
                              void* d_out, int out_size, void* d_ws, size_t ws_size,
                              hipStream_t stream) {
    const float* X    = (const float*)d_in[0];
    const float* U    = (const float*)d_in[1];
    const float* Y    = (const float*)d_in[2];
    const float* W0   = (const float*)d_in[3];
    const float* b0   = (const float*)d_in[4];
    const float* W1   = (const float*)d_in[5];
    const float* b1   = (const float*)d_in[6];
    const float* W2   = (const float*)d_in[7];
    const float* b2   = (const float*)d_in[8];
    const float* Wout = (const float*)d_in[9];
    const float* bout = (const float*)d_in[10];
    float* out = (float*)d_out;

    const size_t need_ws = (size_t)2 * NPTS * HID * sizeof(float);  // 1 MiB
    if (ws_size >= need_ws) {
        float* hX = (float*)d_ws;
        float* hY = hX + NPTS * HID;
        hipLaunchKernelGGL(eotqr_pre, dim3(NPTS), dim3(HID), 0, stream, X, Y, W0, b0, hX, hY);
        (void)hipFuncSetAttribute((const void*)eotqr_mfma<true>,
                                  hipFuncAttributeMaxDynamicSharedMemorySize, LDS_BYTES);
        hipLaunchKernelGGL(eotqr_mfma<true>, dim3(NPTS), dim3(NTH), LDS_BYTES, stream,
                           X, U, Y, W0, b0, W1, b1, W2, b2, Wout, bout, hX, hY, out);
    } else {
        (void)hipFuncSetAttribute((const void*)eotqr_mfma<false>,
                                  hipFuncAttributeMaxDynamicSharedMemorySize, LDS_BYTES);
        hipLaunchKernelGGL(eotqr_mfma<false>, dim3(NPTS), dim3(NTH), LDS_BYTES, stream,
                           X, U, Y, W0, b0, W1, b1, W2, b2, Wout, bout,
                           (const float*)nullptr, (const float*)nullptr, out);
    }
}